// Round 1
// baseline (1957.585 us; speedup 1.0000x reference)
//
#include <hip/hip_runtime.h>
#include <math.h>

#define NN 100000
#define SD 64
#define ND 1000000
#define INDIM 133
#define STRA 140   // LDS row stride for the 64x133 input tile (multiple of 4, 2-way-bank-safe for GEMM reads)
#define STRB 66    // LDS row stride for the 64x64 hidden tile (conflict-free for GEMM reads)

__device__ __forceinline__ float3 f3sub(float3 a, float3 b) {
    return make_float3(a.x - b.x, a.y - b.y, a.z - b.z);
}
__device__ __forceinline__ float3 f3cross(float3 a, float3 b) {
    return make_float3(a.y * b.z - a.z * b.y, a.z * b.x - a.x * b.z, a.x * b.y - a.y * b.x);
}
__device__ __forceinline__ float f3dot(float3 a, float3 b) {
    return a.x * b.x + a.y * b.y + a.z * b.z;
}
__device__ __forceinline__ float3 f3load(const float* __restrict__ p, int idx) {
    const float* q = p + (size_t)idx * 3;
    return make_float3(q[0], q[1], q[2]);
}

__global__ __launch_bounds__(256) void count_kernel(const int* __restrict__ qidx,
                                                    float* __restrict__ cnt_j,
                                                    float* __restrict__ cnt_k) {
    int e = blockIdx.x * 256 + threadIdx.x;
    if (e < ND) {
        atomicAdd(&cnt_j[qidx[ND + e]], 1.0f);
        atomicAdd(&cnt_k[qidx[2 * ND + e]], 1.0f);
    }
}

// One block = one tile of 64 edges. Build inp tile (gather + dihedral + LN) in LDS,
// then 3 register-tiled GEMMs (16x16 thread grid, 4x4 micro-tile), atomic scatter at the end.
__global__ __launch_bounds__(256) void edge_mlp(
    const float* __restrict__ x, const float* __restrict__ pos,
    const int* __restrict__ qidx, const float* __restrict__ qattr,
    const float* __restrict__ gamma, const float* __restrict__ beta,
    const float* __restrict__ w1, const float* __restrict__ b1,
    const float* __restrict__ w2, const float* __restrict__ b2,
    const float* __restrict__ w3, const float* __restrict__ b3,
    float* __restrict__ sum_j, float* __restrict__ sum_k)
{
    __shared__ float A[64 * STRA];   // inp tile (later reused for h2)
    __shared__ float B[64 * STRB];   // h1 tile
    __shared__ int sj[64], sk[64];

    const int tid = threadIdx.x;
    const int el = tid & 63;        // edge within tile
    const int ch = tid >> 6;        // 16-col chunk 0..3
    const int e  = blockIdx.x * 64 + el;

    // ---- gather x[i] and x[l] rows (4 threads per edge, float4 bursts) ----
    {
        int ii = qidx[e];
        int ll = qidx[3 * ND + e];
        const float4* xi = (const float4*)(x + (size_t)ii * SD + ch * 16);
        const float4* xl = (const float4*)(x + (size_t)ll * SD + ch * 16);
        float* row = A + el * STRA;
#pragma unroll
        for (int q = 0; q < 4; ++q) *(float4*)(row + ch * 16 + 4 * q) = xi[q];
#pragma unroll
        for (int q = 0; q < 4; ++q) *(float4*)(row + SD + ch * 16 + 4 * q) = xl[q];
    }

    // ---- dihedral + attr (one thread per edge) ----
    if (tid < 64) {
        int ee = blockIdx.x * 64 + tid;
        int jn = qidx[ND + ee];
        int kn = qidx[2 * ND + ee];
        sj[tid] = jn;
        sk[tid] = kn;
        int in_ = qidx[ee];
        int ln_ = qidx[3 * ND + ee];

        float3 pi = f3load(pos, in_);
        float3 pj = f3load(pos, jn);
        float3 pk = f3load(pos, kn);
        float3 pl = f3load(pos, ln_);

        float3 d1 = f3sub(pj, pi);
        float3 d2 = f3sub(pk, pj);
        float3 d3 = f3sub(pl, pk);
        float3 n1 = f3cross(d1, d2);
        float3 n2 = f3cross(d2, d3);
        float r1 = 1.0f / fmaxf(sqrtf(f3dot(n1, n1)), 1e-6f);
        n1.x *= r1; n1.y *= r1; n1.z *= r1;
        float r2 = 1.0f / fmaxf(sqrtf(f3dot(n2, n2)), 1e-6f);
        n2.x *= r2; n2.y *= r2; n2.z *= r2;
        float cosd = fminf(fmaxf(f3dot(n1, n2), -1.0f), 1.0f);
        float rb = 1.0f / fmaxf(sqrtf(f3dot(d2, d2)), 1e-6f);
        float3 b2n = make_float3(d2.x * rb, d2.y * rb, d2.z * rb);
        float3 m = f3cross(n1, b2n);
        float sind = f3dot(m, n2);

        float* row = A + tid * STRA;
        row[128] = qattr[3 * (size_t)ee + 0];
        row[129] = qattr[3 * (size_t)ee + 1];
        row[130] = qattr[3 * (size_t)ee + 2];
        row[131] = cosd;
        row[132] = sind;
    }
    __syncthreads();

    // ---- LayerNorm over 133 (one thread per edge) ----
    if (tid < 64) {
        float* row = A + tid * STRA;
        float s = 0.0f, ss = 0.0f;
        for (int c = 0; c < INDIM; ++c) {
            float v = row[c];
            s += v;
            ss = fmaf(v, v, ss);
        }
        float mu = s * (1.0f / INDIM);
        float var = ss * (1.0f / INDIM) - mu * mu;
        float rs = rsqrtf(fmaxf(var, 0.0f) + 1e-5f);
        for (int c = 0; c < INDIM; ++c) {
            row[c] = (row[c] - mu) * rs * gamma[c] + beta[c];
        }
    }
    __syncthreads();

    const int tc = tid & 15;   // col group: cols tc*4 .. tc*4+3
    const int tr = tid >> 4;   // row group: rows tr*4 .. tr*4+3
    float acc[4][4];

    // ---- layer 1: h1 = silu(inp @ w1 + b1) -> B ----
#pragma unroll
    for (int i = 0; i < 4; ++i)
#pragma unroll
        for (int j = 0; j < 4; ++j) acc[i][j] = 0.0f;

    for (int c = 0; c < INDIM; ++c) {
        float a0 = A[(tr * 4 + 0) * STRA + c];
        float a1 = A[(tr * 4 + 1) * STRA + c];
        float a2 = A[(tr * 4 + 2) * STRA + c];
        float a3 = A[(tr * 4 + 3) * STRA + c];
        float4 w = *(const float4*)(w1 + c * 64 + tc * 4);
        float wv[4] = {w.x, w.y, w.z, w.w};
        float av[4] = {a0, a1, a2, a3};
#pragma unroll
        for (int i = 0; i < 4; ++i)
#pragma unroll
            for (int j = 0; j < 4; ++j) acc[i][j] = fmaf(av[i], wv[j], acc[i][j]);
    }
    {
        float4 bb = *(const float4*)(b1 + tc * 4);
        float bv[4] = {bb.x, bb.y, bb.z, bb.w};
#pragma unroll
        for (int i = 0; i < 4; ++i)
#pragma unroll
            for (int j = 0; j < 4; ++j) {
                float v = acc[i][j] + bv[j];
                B[(tr * 4 + i) * STRB + tc * 4 + j] = v / (1.0f + expf(-v));
            }
    }
    __syncthreads();

    // ---- layer 2: h2 = silu(h1 @ w2 + b2) -> A (cols 0..63) ----
#pragma unroll
    for (int i = 0; i < 4; ++i)
#pragma unroll
        for (int j = 0; j < 4; ++j) acc[i][j] = 0.0f;

    for (int c = 0; c < 64; ++c) {
        float a0 = B[(tr * 4 + 0) * STRB + c];
        float a1 = B[(tr * 4 + 1) * STRB + c];
        float a2 = B[(tr * 4 + 2) * STRB + c];
        float a3 = B[(tr * 4 + 3) * STRB + c];
        float4 w = *(const float4*)(w2 + c * 64 + tc * 4);
        float wv[4] = {w.x, w.y, w.z, w.w};
        float av[4] = {a0, a1, a2, a3};
#pragma unroll
        for (int i = 0; i < 4; ++i)
#pragma unroll
            for (int j = 0; j < 4; ++j) acc[i][j] = fmaf(av[i], wv[j], acc[i][j]);
    }
    __syncthreads();   // everyone done reading B? (B reads above; A writes below need layer-1/2 reads of A done — they are: layer2 reads only B)
    {
        float4 bb = *(const float4*)(b2 + tc * 4);
        float bv[4] = {bb.x, bb.y, bb.z, bb.w};
#pragma unroll
        for (int i = 0; i < 4; ++i)
#pragma unroll
            for (int j = 0; j < 4; ++j) {
                float v = acc[i][j] + bv[j];
                A[(tr * 4 + i) * STRA + tc * 4 + j] = v / (1.0f + expf(-v));
            }
    }
    __syncthreads();

    // ---- layer 3: msg = h2 @ w3 + b3, scatter-atomics ----
#pragma unroll
    for (int i = 0; i < 4; ++i)
#pragma unroll
        for (int j = 0; j < 4; ++j) acc[i][j] = 0.0f;

    for (int c = 0; c < 64; ++c) {
        float a0 = A[(tr * 4 + 0) * STRA + c];
        float a1 = A[(tr * 4 + 1) * STRA + c];
        float a2 = A[(tr * 4 + 2) * STRA + c];
        float a3 = A[(tr * 4 + 3) * STRA + c];
        float4 w = *(const float4*)(w3 + c * 64 + tc * 4);
        float wv[4] = {w.x, w.y, w.z, w.w};
        float av[4] = {a0, a1, a2, a3};
#pragma unroll
        for (int i = 0; i < 4; ++i)
#pragma unroll
            for (int j = 0; j < 4; ++j) acc[i][j] = fmaf(av[i], wv[j], acc[i][j]);
    }
    {
        float4 bb = *(const float4*)(b3 + tc * 4);
        float bv[4] = {bb.x, bb.y, bb.z, bb.w};
#pragma unroll
        for (int i = 0; i < 4; ++i) {
            int r = tr * 4 + i;
            int jn = sj[r];
            int kn = sk[r];
#pragma unroll
            for (int j = 0; j < 4; ++j) {
                float m = acc[i][j] + bv[j];
                atomicAdd(sum_j + (size_t)jn * 64 + tc * 4 + j, m);
                atomicAdd(sum_k + (size_t)kn * 64 + tc * 4 + j, m);
            }
        }
    }
}

// Final: out[n] = 0.5*(sum_j/cnt_j + sum_k/cnt_k) @ w_out / 8. 16 nodes per block.
__global__ __launch_bounds__(256) void out_kernel(
    const float* __restrict__ sum_j, const float* __restrict__ sum_k,
    const float* __restrict__ cnt_j, const float* __restrict__ cnt_k,
    const float* __restrict__ w_out, float* __restrict__ out)
{
    __shared__ float ag[16 * 66];
    const int tid = threadIdx.x;
    const int n0 = blockIdx.x * 16;
    const int node = tid >> 4;
    const int c4 = (tid & 15) * 4;
    const int n = n0 + node;

    float rj = 1.0f / fmaxf(cnt_j[n], 1.0f);
    float rk = 1.0f / fmaxf(cnt_k[n], 1.0f);
    float4 a = *(const float4*)(sum_j + (size_t)n * 64 + c4);
    float4 b = *(const float4*)(sum_k + (size_t)n * 64 + c4);
    ag[node * 66 + c4 + 0] = 0.5f * (a.x * rj + b.x * rk);
    ag[node * 66 + c4 + 1] = 0.5f * (a.y * rj + b.y * rk);
    ag[node * 66 + c4 + 2] = 0.5f * (a.z * rj + b.z * rk);
    ag[node * 66 + c4 + 3] = 0.5f * (a.w * rj + b.w * rk);
    __syncthreads();

    float acc0 = 0.f, acc1 = 0.f, acc2 = 0.f, acc3 = 0.f;
    for (int c = 0; c < 64; ++c) {
        float av = ag[node * 66 + c];
        float4 w = *(const float4*)(w_out + c * 64 + c4);
        acc0 = fmaf(av, w.x, acc0);
        acc1 = fmaf(av, w.y, acc1);
        acc2 = fmaf(av, w.z, acc2);
        acc3 = fmaf(av, w.w, acc3);
    }
    float4 o;
    o.x = acc0 * 0.125f;
    o.y = acc1 * 0.125f;
    o.z = acc2 * 0.125f;
    o.w = acc3 * 0.125f;
    *(float4*)(out + (size_t)n * 64 + c4) = o;
}

extern "C" void kernel_launch(void* const* d_in, const int* in_sizes, int n_in,
                              void* d_out, int out_size, void* d_ws, size_t ws_size,
                              hipStream_t stream) {
    (void)in_sizes; (void)n_in; (void)out_size; (void)ws_size;

    const float* x     = (const float*)d_in[0];
    const float* pos   = (const float*)d_in[1];
    const int*   qidx  = (const int*)d_in[2];
    const float* qattr = (const float*)d_in[3];
    const float* gamma = (const float*)d_in[4];
    const float* beta  = (const float*)d_in[5];
    const float* w1    = (const float*)d_in[6];
    const float* b1    = (const float*)d_in[7];
    const float* w2    = (const float*)d_in[8];
    const float* b2    = (const float*)d_in[9];
    const float* w3    = (const float*)d_in[10];
    const float* b3    = (const float*)d_in[11];
    const float* w_out = (const float*)d_in[12];
    float* out = (float*)d_out;

    float* sum_j = (float*)d_ws;
    float* sum_k = sum_j + (size_t)NN * 64;
    float* cnt_j = sum_k + (size_t)NN * 64;
    float* cnt_k = cnt_j + NN;
    size_t zero_bytes = ((size_t)NN * 64 * 2 + (size_t)NN * 2) * sizeof(float);

    hipMemsetAsync(d_ws, 0, zero_bytes, stream);
    count_kernel<<<(ND + 255) / 256, 256, 0, stream>>>(qidx, cnt_j, cnt_k);
    edge_mlp<<<ND / 64, 256, 0, stream>>>(x, pos, qidx, qattr, gamma, beta,
                                          w1, b1, w2, b2, w3, b3, sum_j, sum_k);
    out_kernel<<<NN / 16, 256, 0, stream>>>(sum_j, sum_k, cnt_j, cnt_k, w_out, out);
}

// Round 2
// 1339.386 us; speedup vs baseline: 1.4616x; 1.4616x over previous
//
#include <hip/hip_runtime.h>
#include <math.h>

#define NN 100000
#define SD 64
#define ND 1000000
#define INDIM 133
#define STRA 140   // LDS row stride, floats (16B-aligned rows, 2-way-bank-safe)
#define STRB 68    // LDS row stride for hidden tile (16B-aligned rows)
#define NCNT (2*NN)
#define SCAN_CHUNK 2048
#define NBLK_SCAN ((NCNT + SCAN_CHUNK - 1)/SCAN_CHUNK)

__device__ __forceinline__ float3 f3sub(float3 a, float3 b) {
    return make_float3(a.x - b.x, a.y - b.y, a.z - b.z);
}
__device__ __forceinline__ float3 f3cross(float3 a, float3 b) {
    return make_float3(a.y * b.z - a.z * b.y, a.z * b.x - a.x * b.z, a.x * b.y - a.y * b.x);
}
__device__ __forceinline__ float f3dot(float3 a, float3 b) {
    return a.x * b.x + a.y * b.y + a.z * b.z;
}
__device__ __forceinline__ float3 f3load(const float* __restrict__ p, int idx) {
    const float* q = p + (size_t)idx * 3;
    return make_float3(q[0], q[1], q[2]);
}
__device__ __forceinline__ float fsilu(float v) {
    return v / (1.0f + __expf(-v));
}

// ============================ path A: bucket + gather ============================

__global__ __launch_bounds__(256) void count_kernel_i(const int* __restrict__ qidx,
                                                      int* __restrict__ cnt) {
    int e = blockIdx.x * 256 + threadIdx.x;
    if (e < ND) {
        atomicAdd(&cnt[qidx[ND + e]], 1);
        atomicAdd(&cnt[NN + qidx[2 * ND + e]], 1);
    }
}

// block-level exclusive scan over chunks of 2048; writes per-block totals
__global__ __launch_bounds__(256) void scan1(const int* __restrict__ cnt,
                                             int* __restrict__ off,
                                             int* __restrict__ bsum) {
    __shared__ int lds[256];
    const int tid = threadIdx.x;
    const int base = blockIdx.x * SCAN_CHUNK + tid * 8;
    int v[8];
    int tsum = 0;
#pragma unroll
    for (int t = 0; t < 8; ++t) {
        v[t] = (base + t < NCNT) ? cnt[base + t] : 0;
        tsum += v[t];
    }
    lds[tid] = tsum;
    __syncthreads();
    for (int d = 1; d < 256; d <<= 1) {
        int t = 0;
        if (tid >= d) t = lds[tid - d];
        __syncthreads();
        lds[tid] += t;
        __syncthreads();
    }
    if (tid == 255) bsum[blockIdx.x] = lds[255];
    int run = lds[tid] - tsum;   // exclusive prefix of this thread within block
#pragma unroll
    for (int t = 0; t < 8; ++t) {
        if (base + t < NCNT) off[base + t] = run;
        run += v[t];
    }
}

__global__ void scan2(int* __restrict__ bsum) {
    if (threadIdx.x == 0 && blockIdx.x == 0) {
        int run = 0;
        for (int b = 0; b < NBLK_SCAN; ++b) {
            int t = bsum[b];
            bsum[b] = run;
            run += t;
        }
    }
}

__global__ __launch_bounds__(256) void scan3(int* __restrict__ off,
                                             const int* __restrict__ bsum,
                                             int* __restrict__ cur) {
    const int base = blockIdx.x * SCAN_CHUNK + threadIdx.x * 8;
    const int add = bsum[blockIdx.x];
#pragma unroll
    for (int t = 0; t < 8; ++t) {
        int i = base + t;
        if (i < NCNT) {
            int o = off[i] + add;
            off[i] = o;
            cur[i] = o;
        }
    }
    if (blockIdx.x == 0 && threadIdx.x == 0) off[NCNT] = 2 * ND;
}

__global__ __launch_bounds__(256) void fill_kernel(const int* __restrict__ qidx,
                                                   int* __restrict__ cur,
                                                   int* __restrict__ list) {
    int e = blockIdx.x * 256 + threadIdx.x;
    if (e < ND) {
        int j = qidx[ND + e];
        int s = atomicAdd(&cur[j], 1);
        list[s] = e;
        int k = qidx[2 * ND + e];
        int s2 = atomicAdd(&cur[NN + k], 1);
        list[s2] = e;
    }
}

// per-wave node gather + w_out
__global__ __launch_bounds__(256) void node_out(const float* __restrict__ msg,
                                                const int* __restrict__ off,
                                                const int* __restrict__ list,
                                                const float* __restrict__ w_out,
                                                float* __restrict__ out) {
    __shared__ __align__(16) float ag[4][64];
    const int wv = threadIdx.x >> 6;
    const int lane = threadIdx.x & 63;
    const int n = blockIdx.x * 4 + wv;
    if (n < NN) {
        int a0 = off[n], a1 = off[n + 1];
        int b0 = off[NN + n], b1 = off[NN + n + 1];
        float sj = 0.0f, sk = 0.0f;
        for (int p = a0; p < a1; ++p) {
            int e = list[p];
            sj += msg[(size_t)e * 64 + lane];
        }
        for (int p = b0; p < b1; ++p) {
            int e = list[p];
            sk += msg[(size_t)e * 64 + lane];
        }
        float dj = (float)(a1 - a0), dk = (float)(b1 - b0);
        ag[wv][lane] = 0.5f * (sj / fmaxf(dj, 1.0f) + sk / fmaxf(dk, 1.0f));
    }
    __syncthreads();
    if (n < NN) {
        float o = 0.0f;
        for (int q = 0; q < 64; q += 4) {
            float4 a = *(const float4*)&ag[wv][q];
            o = fmaf(a.x, w_out[(q + 0) * 64 + lane], o);
            o = fmaf(a.y, w_out[(q + 1) * 64 + lane], o);
            o = fmaf(a.z, w_out[(q + 2) * 64 + lane], o);
            o = fmaf(a.w, w_out[(q + 3) * 64 + lane], o);
        }
        out[(size_t)n * 64 + lane] = o * 0.125f;
    }
}

// ============================ path B helpers (fallback) ============================

__global__ __launch_bounds__(256) void count_kernel_f(const int* __restrict__ qidx,
                                                      float* __restrict__ cnt_j,
                                                      float* __restrict__ cnt_k) {
    int e = blockIdx.x * 256 + threadIdx.x;
    if (e < ND) {
        atomicAdd(&cnt_j[qidx[ND + e]], 1.0f);
        atomicAdd(&cnt_k[qidx[2 * ND + e]], 1.0f);
    }
}

__global__ __launch_bounds__(256) void out_kernel_b(
    const float* __restrict__ sum_j, const float* __restrict__ sum_k,
    const float* __restrict__ cnt_j, const float* __restrict__ cnt_k,
    const float* __restrict__ w_out, float* __restrict__ out)
{
    __shared__ float ag[16 * 66];
    const int tid = threadIdx.x;
    const int n0 = blockIdx.x * 16;
    const int node = tid >> 4;
    const int c4 = (tid & 15) * 4;
    const int n = n0 + node;

    float rj = 1.0f / fmaxf(cnt_j[n], 1.0f);
    float rk = 1.0f / fmaxf(cnt_k[n], 1.0f);
    float4 a = *(const float4*)(sum_j + (size_t)n * 64 + c4);
    float4 b = *(const float4*)(sum_k + (size_t)n * 64 + c4);
    ag[node * 66 + c4 + 0] = 0.5f * (a.x * rj + b.x * rk);
    ag[node * 66 + c4 + 1] = 0.5f * (a.y * rj + b.y * rk);
    ag[node * 66 + c4 + 2] = 0.5f * (a.z * rj + b.z * rk);
    ag[node * 66 + c4 + 3] = 0.5f * (a.w * rj + b.w * rk);
    __syncthreads();

    float acc0 = 0.f, acc1 = 0.f, acc2 = 0.f, acc3 = 0.f;
    for (int c = 0; c < 64; ++c) {
        float av = ag[node * 66 + c];
        float4 w = *(const float4*)(w_out + c * 64 + c4);
        acc0 = fmaf(av, w.x, acc0);
        acc1 = fmaf(av, w.y, acc1);
        acc2 = fmaf(av, w.z, acc2);
        acc3 = fmaf(av, w.w, acc3);
    }
    float4 o;
    o.x = acc0 * 0.125f;
    o.y = acc1 * 0.125f;
    o.z = acc2 * 0.125f;
    o.w = acc3 * 0.125f;
    *(float4*)(out + (size_t)n * 64 + c4) = o;
}

// ============================ edge MLP (both paths) ============================
// MODE 0: write msg rows.  MODE 1: atomic scatter into sum_j/sum_k.
template <int MODE>
__global__ __launch_bounds__(256) void edge_mlp(
    const float* __restrict__ x, const float* __restrict__ pos,
    const int* __restrict__ qidx, const float* __restrict__ qattr,
    const float* __restrict__ gamma, const float* __restrict__ beta,
    const float* __restrict__ w1, const float* __restrict__ b1,
    const float* __restrict__ w2, const float* __restrict__ b2,
    const float* __restrict__ w3, const float* __restrict__ b3,
    float* __restrict__ msg, float* __restrict__ sum_j, float* __restrict__ sum_k)
{
    __shared__ __align__(16) float A[64 * STRA];   // inp tile (later h2)
    __shared__ __align__(16) float B[64 * STRB];   // h1 tile
    __shared__ float psum[4][64], psq[4][64];
    __shared__ int sj[64], sk[64];

    const int tid = threadIdx.x;
    const int el = tid & 63;        // edge within tile
    const int ch = tid >> 6;        // chunk 0..3
    const int eb = blockIdx.x * 64;
    const int e  = eb + el;

    // ---- gather x[i] and x[l] rows (4 threads per edge, float4 bursts) ----
    {
        int ii = qidx[e];
        int ll = qidx[3 * ND + e];
        const float4* xi = (const float4*)(x + (size_t)ii * SD + ch * 16);
        const float4* xl = (const float4*)(x + (size_t)ll * SD + ch * 16);
        float* row = A + el * STRA;
#pragma unroll
        for (int q = 0; q < 4; ++q) *(float4*)(row + ch * 16 + 4 * q) = xi[q];
#pragma unroll
        for (int q = 0; q < 4; ++q) *(float4*)(row + SD + ch * 16 + 4 * q) = xl[q];
    }

    // ---- dihedral + attr (one thread per edge) ----
    if (tid < 64) {
        int ee = eb + tid;
        int jn = qidx[ND + ee];
        int kn = qidx[2 * ND + ee];
        sj[tid] = jn;
        sk[tid] = kn;
        int in_ = qidx[ee];
        int ln_ = qidx[3 * ND + ee];

        float3 pi = f3load(pos, in_);
        float3 pj = f3load(pos, jn);
        float3 pk = f3load(pos, kn);
        float3 pl = f3load(pos, ln_);

        float3 d1 = f3sub(pj, pi);
        float3 d2 = f3sub(pk, pj);
        float3 d3 = f3sub(pl, pk);
        float3 n1 = f3cross(d1, d2);
        float3 n2 = f3cross(d2, d3);
        float r1 = 1.0f / fmaxf(sqrtf(f3dot(n1, n1)), 1e-6f);
        n1.x *= r1; n1.y *= r1; n1.z *= r1;
        float r2 = 1.0f / fmaxf(sqrtf(f3dot(n2, n2)), 1e-6f);
        n2.x *= r2; n2.y *= r2; n2.z *= r2;
        float cosd = fminf(fmaxf(f3dot(n1, n2), -1.0f), 1.0f);
        float rb = 1.0f / fmaxf(sqrtf(f3dot(d2, d2)), 1e-6f);
        float3 b2n = make_float3(d2.x * rb, d2.y * rb, d2.z * rb);
        float3 m = f3cross(n1, b2n);
        float sind = f3dot(m, n2);

        float* row = A + tid * STRA;
        row[128] = qattr[3 * (size_t)ee + 0];
        row[129] = qattr[3 * (size_t)ee + 1];
        row[130] = qattr[3 * (size_t)ee + 2];
        row[131] = cosd;
        row[132] = sind;
    }
    __syncthreads();

    // ---- LayerNorm over 133, 4 threads per row ----
    {
        const float* row = A + el * STRA;
        int c0 = ch * 34, c1 = (c0 + 34 < INDIM) ? c0 + 34 : INDIM;
        float s = 0.0f, ss = 0.0f;
        for (int c = c0; c < c1; ++c) {
            float v = row[c];
            s += v;
            ss = fmaf(v, v, ss);
        }
        psum[ch][el] = s;
        psq[ch][el] = ss;
    }
    __syncthreads();
    {
        float s  = psum[0][el] + psum[1][el] + psum[2][el] + psum[3][el];
        float ss = psq[0][el] + psq[1][el] + psq[2][el] + psq[3][el];
        float mu = s * (1.0f / INDIM);
        float var = ss * (1.0f / INDIM) - mu * mu;
        float rs = rsqrtf(fmaxf(var, 0.0f) + 1e-5f);
        float* row = A + el * STRA;
        int c0 = ch * 34, c1 = (c0 + 34 < INDIM) ? c0 + 34 : INDIM;
        for (int c = c0; c < c1; ++c)
            row[c] = (row[c] - mu) * rs * gamma[c] + beta[c];
    }
    __syncthreads();

    const int tc = tid & 15;   // col group: cols tc*4 .. tc*4+3
    const int tr = tid >> 4;   // row group: rows tr*4 .. tr*4+3
    float acc[4][4];

    // ---- layer 1: h1 = silu(inp @ w1 + b1) -> B ----
#pragma unroll
    for (int i = 0; i < 4; ++i)
#pragma unroll
        for (int j = 0; j < 4; ++j) acc[i][j] = 0.0f;

    for (int c4 = 0; c4 < 33; ++c4) {
        const int c = c4 * 4;
        float4 wv0 = *(const float4*)(w1 + (size_t)(c + 0) * 64 + tc * 4);
        float4 wv1 = *(const float4*)(w1 + (size_t)(c + 1) * 64 + tc * 4);
        float4 wv2 = *(const float4*)(w1 + (size_t)(c + 2) * 64 + tc * 4);
        float4 wv3 = *(const float4*)(w1 + (size_t)(c + 3) * 64 + tc * 4);
        const float* wp[4] = {(const float*)&wv0, (const float*)&wv1,
                              (const float*)&wv2, (const float*)&wv3};
#pragma unroll
        for (int i = 0; i < 4; ++i) {
            float4 av = *(const float4*)(A + (tr * 4 + i) * STRA + c);
            const float* ap = (const float*)&av;
#pragma unroll
            for (int q = 0; q < 4; ++q)
#pragma unroll
                for (int j = 0; j < 4; ++j)
                    acc[i][j] = fmaf(ap[q], wp[q][j], acc[i][j]);
        }
    }
    {   // tail column 132
        float4 wt = *(const float4*)(w1 + (size_t)132 * 64 + tc * 4);
        const float* wp = (const float*)&wt;
#pragma unroll
        for (int i = 0; i < 4; ++i) {
            float a = A[(tr * 4 + i) * STRA + 132];
#pragma unroll
            for (int j = 0; j < 4; ++j) acc[i][j] = fmaf(a, wp[j], acc[i][j]);
        }
    }
    {
        float4 bb = *(const float4*)(b1 + tc * 4);
        const float* bv = (const float*)&bb;
#pragma unroll
        for (int i = 0; i < 4; ++i)
#pragma unroll
            for (int j = 0; j < 4; ++j)
                B[(tr * 4 + i) * STRB + tc * 4 + j] = fsilu(acc[i][j] + bv[j]);
    }
    __syncthreads();

    // ---- layer 2: h2 = silu(h1 @ w2 + b2) -> A (cols 0..63) ----
#pragma unroll
    for (int i = 0; i < 4; ++i)
#pragma unroll
        for (int j = 0; j < 4; ++j) acc[i][j] = 0.0f;

    for (int c4 = 0; c4 < 16; ++c4) {
        const int c = c4 * 4;
        float4 wv0 = *(const float4*)(w2 + (size_t)(c + 0) * 64 + tc * 4);
        float4 wv1 = *(const float4*)(w2 + (size_t)(c + 1) * 64 + tc * 4);
        float4 wv2 = *(const float4*)(w2 + (size_t)(c + 2) * 64 + tc * 4);
        float4 wv3 = *(const float4*)(w2 + (size_t)(c + 3) * 64 + tc * 4);
        const float* wp[4] = {(const float*)&wv0, (const float*)&wv1,
                              (const float*)&wv2, (const float*)&wv3};
#pragma unroll
        for (int i = 0; i < 4; ++i) {
            float4 av = *(const float4*)(B + (tr * 4 + i) * STRB + c);
            const float* ap = (const float*)&av;
#pragma unroll
            for (int q = 0; q < 4; ++q)
#pragma unroll
                for (int j = 0; j < 4; ++j)
                    acc[i][j] = fmaf(ap[q], wp[q][j], acc[i][j]);
        }
    }
    __syncthreads();   // ensure all layer-1 reads of A are long done & all layer-2 B reads done before A overwrite
    {
        float4 bb = *(const float4*)(b2 + tc * 4);
        const float* bv = (const float*)&bb;
#pragma unroll
        for (int i = 0; i < 4; ++i)
#pragma unroll
            for (int j = 0; j < 4; ++j)
                A[(tr * 4 + i) * STRA + tc * 4 + j] = fsilu(acc[i][j] + bv[j]);
    }
    __syncthreads();

    // ---- layer 3: msg = h2 @ w3 + b3 ----
#pragma unroll
    for (int i = 0; i < 4; ++i)
#pragma unroll
        for (int j = 0; j < 4; ++j) acc[i][j] = 0.0f;

    for (int c4 = 0; c4 < 16; ++c4) {
        const int c = c4 * 4;
        float4 wv0 = *(const float4*)(w3 + (size_t)(c + 0) * 64 + tc * 4);
        float4 wv1 = *(const float4*)(w3 + (size_t)(c + 1) * 64 + tc * 4);
        float4 wv2 = *(const float4*)(w3 + (size_t)(c + 2) * 64 + tc * 4);
        float4 wv3 = *(const float4*)(w3 + (size_t)(c + 3) * 64 + tc * 4);
        const float* wp[4] = {(const float*)&wv0, (const float*)&wv1,
                              (const float*)&wv2, (const float*)&wv3};
#pragma unroll
        for (int i = 0; i < 4; ++i) {
            float4 av = *(const float4*)(A + (tr * 4 + i) * STRA + c);
            const float* ap = (const float*)&av;
#pragma unroll
            for (int q = 0; q < 4; ++q)
#pragma unroll
                for (int j = 0; j < 4; ++j)
                    acc[i][j] = fmaf(ap[q], wp[q][j], acc[i][j]);
        }
    }
    {
        float4 bb = *(const float4*)(b3 + tc * 4);
        const float* bv = (const float*)&bb;
        if (MODE == 0) {
#pragma unroll
            for (int i = 0; i < 4; ++i) {
                float4 v;
                v.x = acc[i][0] + bv[0];
                v.y = acc[i][1] + bv[1];
                v.z = acc[i][2] + bv[2];
                v.w = acc[i][3] + bv[3];
                *(float4*)(msg + (size_t)(eb + tr * 4 + i) * 64 + tc * 4) = v;
            }
        } else {
#pragma unroll
            for (int i = 0; i < 4; ++i) {
                int r = tr * 4 + i;
                int jn = sj[r];
                int kn = sk[r];
#pragma unroll
                for (int j = 0; j < 4; ++j) {
                    float m = acc[i][j] + bv[j];
                    atomicAdd(sum_j + (size_t)jn * 64 + tc * 4 + j, m);
                    atomicAdd(sum_k + (size_t)kn * 64 + tc * 4 + j, m);
                }
            }
        }
    }
}

// ============================ launch ============================

extern "C" void kernel_launch(void* const* d_in, const int* in_sizes, int n_in,
                              void* d_out, int out_size, void* d_ws, size_t ws_size,
                              hipStream_t stream) {
    (void)in_sizes; (void)n_in; (void)out_size;

    const float* x     = (const float*)d_in[0];
    const float* pos   = (const float*)d_in[1];
    const int*   qidx  = (const int*)d_in[2];
    const float* qattr = (const float*)d_in[3];
    const float* gamma = (const float*)d_in[4];
    const float* beta  = (const float*)d_in[5];
    const float* w1    = (const float*)d_in[6];
    const float* b1    = (const float*)d_in[7];
    const float* w2    = (const float*)d_in[8];
    const float* b2    = (const float*)d_in[9];
    const float* w3    = (const float*)d_in[10];
    const float* b3    = (const float*)d_in[11];
    const float* w_out = (const float*)d_in[12];
    float* out = (float*)d_out;

    // path-A workspace layout
    size_t o = 0;
    const size_t msg_off = o;            o += (size_t)ND * 64 * 4;      o = (o + 255) & ~(size_t)255;
    const size_t off_off = o;            o += (size_t)(NCNT + 1) * 4;   o = (o + 255) & ~(size_t)255;
    const size_t cur_off = o;            o += (size_t)NCNT * 4;         o = (o + 255) & ~(size_t)255;
    const size_t bsum_off = o;           o += (size_t)NBLK_SCAN * 4;    o = (o + 255) & ~(size_t)255;
    const size_t list_off = o;           o += (size_t)2 * ND * 4;
    const size_t needA = o;

    if (ws_size >= needA) {
        // ---- path A: bucket + gather, no f32 scatter atomics ----
        char* w = (char*)d_ws;
        float* msg = (float*)(w + msg_off);
        int* off   = (int*)(w + off_off);
        int* cur   = (int*)(w + cur_off);
        int* bsum  = (int*)(w + bsum_off);
        int* list  = (int*)(w + list_off);

        hipMemsetAsync(cur, 0, (size_t)NCNT * 4, stream);
        count_kernel_i<<<(ND + 255) / 256, 256, 0, stream>>>(qidx, cur);
        scan1<<<NBLK_SCAN, 256, 0, stream>>>(cur, off, bsum);
        scan2<<<1, 64, 0, stream>>>(bsum);
        scan3<<<NBLK_SCAN, 256, 0, stream>>>(off, bsum, cur);
        fill_kernel<<<(ND + 255) / 256, 256, 0, stream>>>(qidx, cur, list);
        edge_mlp<0><<<ND / 64, 256, 0, stream>>>(x, pos, qidx, qattr, gamma, beta,
                                                 w1, b1, w2, b2, w3, b3,
                                                 msg, nullptr, nullptr);
        node_out<<<(NN + 3) / 4, 256, 0, stream>>>(msg, off, list, w_out, out);
    } else {
        // ---- path B: round-1 atomic fallback ----
        float* sum_j = (float*)d_ws;
        float* sum_k = sum_j + (size_t)NN * 64;
        float* cnt_j = sum_k + (size_t)NN * 64;
        float* cnt_k = cnt_j + NN;
        size_t zero_bytes = ((size_t)NN * 64 * 2 + (size_t)NN * 2) * sizeof(float);

        hipMemsetAsync(d_ws, 0, zero_bytes, stream);
        count_kernel_f<<<(ND + 255) / 256, 256, 0, stream>>>(qidx, cnt_j, cnt_k);
        edge_mlp<1><<<ND / 64, 256, 0, stream>>>(x, pos, qidx, qattr, gamma, beta,
                                                 w1, b1, w2, b2, w3, b3,
                                                 nullptr, sum_j, sum_k);
        out_kernel_b<<<NN / 16, 256, 0, stream>>>(sum_j, sum_k, cnt_j, cnt_k, w_out, out);
    }
}

// Round 3
// 929.303 us; speedup vs baseline: 2.1065x; 1.4413x over previous
//
#include <hip/hip_runtime.h>
#include <math.h>

#define NN 100000
#define ND 1000000
#define INDIM 133
#define K1P 160                 // padded input dim (5 x 32)
#define NCNT (2*NN)
#define SCAN_CHUNK 2048
#define NBLK_SCAN ((NCNT + SCAN_CHUNK - 1) / SCAN_CHUNK)
#define HS 72                   // LDS h-tile row stride in bf16 elems (144B: 2-way-bank-safe)

typedef __bf16 bf16x8 __attribute__((ext_vector_type(8)));
typedef float  f32x4  __attribute__((ext_vector_type(4)));
typedef _Float16 f16;

__device__ __forceinline__ f32x4 mfma_bf16(bf16x8 a, bf16x8 b, f32x4 c) {
    return __builtin_amdgcn_mfma_f32_16x16x32_bf16(a, b, c, 0, 0, 0);
}

__device__ __forceinline__ float3 f3sub(float3 a, float3 b) {
    return make_float3(a.x - b.x, a.y - b.y, a.z - b.z);
}
__device__ __forceinline__ float3 f3cross(float3 a, float3 b) {
    return make_float3(a.y * b.z - a.z * b.y, a.z * b.x - a.x * b.z, a.x * b.y - a.y * b.x);
}
__device__ __forceinline__ float f3dot(float3 a, float3 b) {
    return a.x * b.x + a.y * b.y + a.z * b.z;
}
__device__ __forceinline__ float3 f3load(const float* __restrict__ p, int idx) {
    const float* q = p + (size_t)idx * 3;
    return make_float3(q[0], q[1], q[2]);
}
__device__ __forceinline__ float fsilu(float v) {
    return v / (1.0f + __expf(-v));
}

// ---- weight prep: transpose to [n][k], pad K, split into bf16 hi+lo ----
__global__ __launch_bounds__(256) void prep_w(const float* __restrict__ w,
                                              __bf16* __restrict__ hi,
                                              __bf16* __restrict__ lo,
                                              int K, int KP) {
    int idx = blockIdx.x * 256 + threadIdx.x;
    if (idx >= 64 * KP) return;
    int n = idx / KP, kp = idx - n * KP;
    float v = (kp < K) ? w[(size_t)kp * 64 + n] : 0.0f;
    __bf16 h = (__bf16)v;
    hi[idx] = h;
    lo[idx] = (__bf16)(v - (float)h);
}

__global__ void prep_gb(const float* __restrict__ g, const float* __restrict__ b,
                        float* __restrict__ gp, float* __restrict__ bp) {
    int i = threadIdx.x;
    if (i < K1P) {
        gp[i] = (i < INDIM) ? g[i] : 0.0f;
        bp[i] = (i < INDIM) ? b[i] : 0.0f;
    }
}

// ---- counting sort machinery (counts -> in-place exclusive scan -> slots) ----
__global__ __launch_bounds__(256) void count_kernel(const int* __restrict__ qidx,
                                                    int* __restrict__ cnt) {
    int e = blockIdx.x * 256 + threadIdx.x;
    if (e < ND) {
        atomicAdd(&cnt[qidx[ND + e]], 1);
        atomicAdd(&cnt[NN + qidx[2 * ND + e]], 1);
    }
}

// in-place block exclusive scan over chunks of 2048 (each thread reads its 8 before writing)
__global__ __launch_bounds__(256) void scan1(int* data, int* __restrict__ bsum) {
    __shared__ int lds[256];
    const int tid = threadIdx.x;
    const int base = blockIdx.x * SCAN_CHUNK + tid * 8;
    int v[8];
    int tsum = 0;
#pragma unroll
    for (int t = 0; t < 8; ++t) {
        v[t] = (base + t < NCNT) ? data[base + t] : 0;
        tsum += v[t];
    }
    lds[tid] = tsum;
    __syncthreads();
    for (int d = 1; d < 256; d <<= 1) {
        int t = 0;
        if (tid >= d) t = lds[tid - d];
        __syncthreads();
        lds[tid] += t;
        __syncthreads();
    }
    if (tid == 255) bsum[blockIdx.x] = lds[255];
    int run = lds[tid] - tsum;
#pragma unroll
    for (int t = 0; t < 8; ++t) {
        if (base + t < NCNT) data[base + t] = run;
        run += v[t];
    }
}

__global__ void scan2(int* __restrict__ bsum) {
    if (threadIdx.x == 0 && blockIdx.x == 0) {
        int run = 0;
        for (int b = 0; b < NBLK_SCAN; ++b) {
            int t = bsum[b];
            bsum[b] = run;
            run += t;
        }
    }
}

__global__ __launch_bounds__(256) void scan3(int* __restrict__ off,
                                             const int* __restrict__ bsum) {
    const int base = blockIdx.x * SCAN_CHUNK + threadIdx.x * 8;
    const int add = bsum[blockIdx.x];
#pragma unroll
    for (int t = 0; t < 8; ++t) {
        int i = base + t;
        if (i < NCNT) off[i] += add;
    }
}

// fill: slot per incidence; mutates off so that afterwards off[b] = END of bucket b
// (bucket b's start = b==0 ? 0 : off[b-1])
__global__ __launch_bounds__(256) void fill_kernel(const int* __restrict__ qidx,
                                                   int* __restrict__ off,
                                                   int* __restrict__ slot_j,
                                                   int* __restrict__ slot_k) {
    int e = blockIdx.x * 256 + threadIdx.x;
    if (e < ND) {
        slot_j[e] = atomicAdd(&off[qidx[ND + e]], 1);
        slot_k[e] = atomicAdd(&off[NN + qidx[2 * ND + e]], 1);
    }
}

// ---- edge MLP: per-wave 16 edges, split-bf16 MFMA, no __syncthreads ----
// A-frag convention (m92/m97-verified): lane l <- row (l&15), k = (l>>4)*8 + j, 8 contiguous.
// B from transposed weights wT[n][k]: lane l <- col-row (l&15), same k slice.
// C/D (m89-verified): col = lane&15, row = (lane>>4)*4 + reg.
__global__ __launch_bounds__(256) void edge_mlp_mfma(
    const float* __restrict__ x, const float* __restrict__ pos,
    const int* __restrict__ qidx, const float* __restrict__ qattr,
    const float* __restrict__ gp, const float* __restrict__ bp,
    const __bf16* __restrict__ w1h, const __bf16* __restrict__ w1l, const float* __restrict__ b1,
    const __bf16* __restrict__ w2h, const __bf16* __restrict__ w2l, const float* __restrict__ b2,
    const __bf16* __restrict__ w3h, const __bf16* __restrict__ w3l, const float* __restrict__ b3,
    const int* __restrict__ slot_j, const int* __restrict__ slot_k,
    f16* __restrict__ msg)
{
    // per-wave private 16x64 h tiles (hi/lo), stride 72 bf16 = 144B (2-way banks only)
    __shared__ __align__(16) __bf16 hsh[4][16 * HS];
    __shared__ __align__(16) __bf16 hsl[4][16 * HS];

    const int tid = threadIdx.x;
    const int w   = tid >> 6;
    const int l   = tid & 63;
    const int m   = l & 15;    // A-row / B-col / msg col-base within tile
    const int kg  = l >> 4;    // k-group 0..3
    const int ebase = blockIdx.x * 64 + w * 16;
    const int e   = ebase + m;

    const int i_ = qidx[e];
    const int j_ = qidx[ND + e];
    const int k_ = qidx[2 * ND + e];
    const int l_ = qidx[3 * ND + e];

    // ---- dihedral (each lane computes its own row's; only kg==0 slots keep it) ----
    float cosd, sind;
    {
        float3 pi = f3load(pos, i_), pj = f3load(pos, j_);
        float3 pk = f3load(pos, k_), pl = f3load(pos, l_);
        float3 d1 = f3sub(pj, pi);
        float3 d2 = f3sub(pk, pj);
        float3 d3 = f3sub(pl, pk);
        float3 n1 = f3cross(d1, d2);
        float3 n2 = f3cross(d2, d3);
        float r1 = 1.0f / fmaxf(sqrtf(f3dot(n1, n1)), 1e-6f);
        n1.x *= r1; n1.y *= r1; n1.z *= r1;
        float r2 = 1.0f / fmaxf(sqrtf(f3dot(n2, n2)), 1e-6f);
        n2.x *= r2; n2.y *= r2; n2.z *= r2;
        cosd = fminf(fmaxf(f3dot(n1, n2), -1.0f), 1.0f);
        float rb = 1.0f / fmaxf(sqrtf(f3dot(d2, d2)), 1e-6f);
        float3 b2n = make_float3(d2.x * rb, d2.y * rb, d2.z * rb);
        float3 mm = f3cross(n1, b2n);
        sind = f3dot(mm, n2);
    }
    float at0 = qattr[(size_t)e * 3 + 0];
    float at1 = qattr[(size_t)e * 3 + 1];
    float at2 = qattr[(size_t)e * 3 + 2];

    // ---- gather this lane's k-slices of inp row m: cols 32s+8kg .. +7 ----
    float af[5][8] __attribute__((aligned(16)));
    {
        const float* xi = x + (size_t)i_ * 64 + 8 * kg;
        const float* xl = x + (size_t)l_ * 64 + 8 * kg;
        *(float4*)&af[0][0] = *(const float4*)(xi);
        *(float4*)&af[0][4] = *(const float4*)(xi + 4);
        *(float4*)&af[1][0] = *(const float4*)(xi + 32);
        *(float4*)&af[1][4] = *(const float4*)(xi + 36);
        *(float4*)&af[2][0] = *(const float4*)(xl);
        *(float4*)&af[2][4] = *(const float4*)(xl + 4);
        *(float4*)&af[3][0] = *(const float4*)(xl + 32);
        *(float4*)&af[3][4] = *(const float4*)(xl + 36);
        float g0 = (kg == 0) ? 1.0f : 0.0f;   // cols 128-132 live in kg==0's s=4 slice
        af[4][0] = at0 * g0;
        af[4][1] = at1 * g0;
        af[4][2] = at2 * g0;
        af[4][3] = cosd * g0;
        af[4][4] = sind * g0;
        af[4][5] = 0.0f; af[4][6] = 0.0f; af[4][7] = 0.0f;
    }

    // ---- LayerNorm over 133 via 4-lane butterfly (lanes m, m+16, m+32, m+48) ----
    float s1 = 0.0f, s2 = 0.0f;
#pragma unroll
    for (int s = 0; s < 5; ++s)
#pragma unroll
        for (int j = 0; j < 8; ++j) {
            float v = af[s][j];
            s1 += v;
            s2 = fmaf(v, v, s2);
        }
    s1 += __shfl_xor(s1, 16); s1 += __shfl_xor(s1, 32);
    s2 += __shfl_xor(s2, 16); s2 += __shfl_xor(s2, 32);
    const float mu  = s1 * (1.0f / INDIM);
    const float var = s2 * (1.0f / INDIM) - mu * mu;
    const float rs  = rsqrtf(fmaxf(var, 0.0f) + 1e-5f);

    // ---- normalize, split hi/lo bf16 A-frags (padded cols have gamma=beta=0 -> exact 0) ----
    bf16x8 ah[5], al[5];
#pragma unroll
    for (int s = 0; s < 5; ++s) {
        const float* gpp = gp + 32 * s + 8 * kg;
        const float* bpp = bp + 32 * s + 8 * kg;
#pragma unroll
        for (int j = 0; j < 8; ++j) {
            float v = (af[s][j] - mu) * rs * gpp[j] + bpp[j];
            __bf16 h = (__bf16)v;
            ah[s][j] = h;
            al[s][j] = (__bf16)(v - (float)h);
        }
    }

    // ---- layer 1: K=160, 5 k-steps, 4 n-tiles, split 3-MFMA ----
    f32x4 acc[4];
#pragma unroll
    for (int nt = 0; nt < 4; ++nt) acc[nt] = (f32x4){0.f, 0.f, 0.f, 0.f};
#pragma unroll
    for (int s = 0; s < 5; ++s) {
#pragma unroll
        for (int nt = 0; nt < 4; ++nt) {
            const size_t wb = (size_t)(16 * nt + m) * K1P + 32 * s + 8 * kg;
            bf16x8 bh = *(const bf16x8*)(w1h + wb);
            bf16x8 bl = *(const bf16x8*)(w1l + wb);
            acc[nt] = mfma_bf16(ah[s], bh, acc[nt]);
            acc[nt] = mfma_bf16(al[s], bh, acc[nt]);
            acc[nt] = mfma_bf16(ah[s], bl, acc[nt]);
        }
    }

    // ---- bias + silu + write h1 (hi/lo) to per-wave LDS tile (C-layout) ----
    __bf16* hhw = &hsh[w][0];
    __bf16* hlw = &hsl[w][0];
#pragma unroll
    for (int nt = 0; nt < 4; ++nt) {
        float bb = b1[16 * nt + m];
#pragma unroll
        for (int r = 0; r < 4; ++r) {
            float hv = fsilu(acc[nt][r] + bb);
            __bf16 h = (__bf16)hv;
            int o = (4 * kg + r) * HS + 16 * nt + m;
            hhw[o] = h;
            hlw[o] = (__bf16)(hv - (float)h);
        }
    }

    // ---- layer 2: read A-frags of h1 (same-wave DS in-order; no barrier needed) ----
    bf16x8 a2h[2], a2l[2];
#pragma unroll
    for (int s = 0; s < 2; ++s) {
        a2h[s] = *(const bf16x8*)(hhw + m * HS + 32 * s + 8 * kg);
        a2l[s] = *(const bf16x8*)(hlw + m * HS + 32 * s + 8 * kg);
    }
    f32x4 acc2[4];
#pragma unroll
    for (int nt = 0; nt < 4; ++nt) acc2[nt] = (f32x4){0.f, 0.f, 0.f, 0.f};
#pragma unroll
    for (int s = 0; s < 2; ++s) {
#pragma unroll
        for (int nt = 0; nt < 4; ++nt) {
            const size_t wb = (size_t)(16 * nt + m) * 64 + 32 * s + 8 * kg;
            bf16x8 bh = *(const bf16x8*)(w2h + wb);
            bf16x8 bl = *(const bf16x8*)(w2l + wb);
            acc2[nt] = mfma_bf16(a2h[s], bh, acc2[nt]);
            acc2[nt] = mfma_bf16(a2l[s], bh, acc2[nt]);
            acc2[nt] = mfma_bf16(a2h[s], bl, acc2[nt]);
        }
    }
    // h2 overwrites the same tiles (reads above already issued in-order before these writes)
#pragma unroll
    for (int nt = 0; nt < 4; ++nt) {
        float bb = b2[16 * nt + m];
#pragma unroll
        for (int r = 0; r < 4; ++r) {
            float hv = fsilu(acc2[nt][r] + bb);
            __bf16 h = (__bf16)hv;
            int o = (4 * kg + r) * HS + 16 * nt + m;
            hhw[o] = h;
            hlw[o] = (__bf16)(hv - (float)h);
        }
    }

    // ---- layer 3 ----
    bf16x8 a3h[2], a3l[2];
#pragma unroll
    for (int s = 0; s < 2; ++s) {
        a3h[s] = *(const bf16x8*)(hhw + m * HS + 32 * s + 8 * kg);
        a3l[s] = *(const bf16x8*)(hlw + m * HS + 32 * s + 8 * kg);
    }
    f32x4 acc3[4];
#pragma unroll
    for (int nt = 0; nt < 4; ++nt) acc3[nt] = (f32x4){0.f, 0.f, 0.f, 0.f};
#pragma unroll
    for (int s = 0; s < 2; ++s) {
#pragma unroll
        for (int nt = 0; nt < 4; ++nt) {
            const size_t wb = (size_t)(16 * nt + m) * 64 + 32 * s + 8 * kg;
            bf16x8 bh = *(const bf16x8*)(w3h + wb);
            bf16x8 bl = *(const bf16x8*)(w3l + wb);
            acc3[nt] = mfma_bf16(a3h[s], bh, acc3[nt]);
            acc3[nt] = mfma_bf16(a3l[s], bh, acc3[nt]);
            acc3[nt] = mfma_bf16(a3h[s], bl, acc3[nt]);
        }
    }

    // ---- msg: write f16 rows to both sorted slot positions ----
    float b3v[4];
#pragma unroll
    for (int nt = 0; nt < 4; ++nt) b3v[nt] = b3[16 * nt + m];
#pragma unroll
    for (int r = 0; r < 4; ++r) {
        int er = ebase + 4 * kg + r;          // C-row = edge 4kg+r of this wave
        size_t sj = (size_t)slot_j[er] * 64 + m;
        size_t sk = (size_t)slot_k[er] * 64 + m;
#pragma unroll
        for (int nt = 0; nt < 4; ++nt) {
            f16 hv = (f16)(acc3[nt][r] + b3v[nt]);
            msg[sj + 16 * nt] = hv;
            msg[sk + 16 * nt] = hv;
        }
    }
}

// ---- node aggregation: sequential slot ranges + w_out cached in 64 VGPRs ----
__global__ __launch_bounds__(256) void node_out(const f16* __restrict__ msg,
                                                const int* __restrict__ off,
                                                const float* __restrict__ w_out,
                                                float* __restrict__ out) {
    __shared__ float ag[4][64];
    const int w = threadIdx.x >> 6;
    const int lane = threadIdx.x & 63;
    float wc[64];
#pragma unroll
    for (int c = 0; c < 64; ++c) wc[c] = w_out[(size_t)c * 64 + lane];

    for (int n = blockIdx.x * 4 + w; n < NN; n += gridDim.x * 4) {
        int ja = (n == 0) ? 0 : off[n - 1];
        int jb = off[n];
        int ka = off[NN + n - 1];             // n==0 -> off[NN-1] = start of k-region
        int kb = off[NN + n];
        float sj = 0.0f;
        for (int p = ja; p < jb; ++p) sj += (float)msg[(size_t)p * 64 + lane];
        float sk = 0.0f;
        for (int p = ka; p < kb; ++p) sk += (float)msg[(size_t)p * 64 + lane];
        float a = 0.5f * (sj / fmaxf((float)(jb - ja), 1.0f) +
                          sk / fmaxf((float)(kb - ka), 1.0f));
        ag[w][lane] = a;   // same-wave DS ordering: broadcast reads below see this write
        float o0 = 0.f, o1 = 0.f, o2 = 0.f, o3 = 0.f;
#pragma unroll
        for (int c = 0; c < 64; c += 4) {
            o0 = fmaf(ag[w][c + 0], wc[c + 0], o0);
            o1 = fmaf(ag[w][c + 1], wc[c + 1], o1);
            o2 = fmaf(ag[w][c + 2], wc[c + 2], o2);
            o3 = fmaf(ag[w][c + 3], wc[c + 3], o3);
        }
        out[(size_t)n * 64 + lane] = (o0 + o1 + o2 + o3) * 0.125f;
    }
}

// ============================ launch ============================

extern "C" void kernel_launch(void* const* d_in, const int* in_sizes, int n_in,
                              void* d_out, int out_size, void* d_ws, size_t ws_size,
                              hipStream_t stream) {
    (void)in_sizes; (void)n_in; (void)out_size;

    const float* x     = (const float*)d_in[0];
    const float* pos   = (const float*)d_in[1];
    const int*   qidx  = (const int*)d_in[2];
    const float* qattr = (const float*)d_in[3];
    const float* gamma = (const float*)d_in[4];
    const float* beta  = (const float*)d_in[5];
    const float* w1    = (const float*)d_in[6];
    const float* b1    = (const float*)d_in[7];
    const float* w2    = (const float*)d_in[8];
    const float* b2    = (const float*)d_in[9];
    const float* w3    = (const float*)d_in[10];
    const float* b3    = (const float*)d_in[11];
    const float* w_out = (const float*)d_in[12];
    float* out = (float*)d_out;

    // workspace layout (256-aligned)
    size_t o = 0;
    auto alloc = [&](size_t bytes) { size_t r = o; o = (o + bytes + 255) & ~(size_t)255; return r; };
    char* W = (char*)d_ws;
    f16*    msg    = (f16*)   (W + alloc((size_t)2 * ND * 64 * sizeof(f16)));
    int*    slot_j = (int*)   (W + alloc((size_t)ND * sizeof(int)));
    int*    slot_k = (int*)   (W + alloc((size_t)ND * sizeof(int)));
    int*    off    = (int*)   (W + alloc((size_t)NCNT * sizeof(int)));
    int*    bsum   = (int*)   (W + alloc((size_t)NBLK_SCAN * sizeof(int)));
    __bf16* w1h    = (__bf16*)(W + alloc((size_t)64 * K1P * sizeof(__bf16)));
    __bf16* w1l    = (__bf16*)(W + alloc((size_t)64 * K1P * sizeof(__bf16)));
    __bf16* w2h    = (__bf16*)(W + alloc((size_t)64 * 64 * sizeof(__bf16)));
    __bf16* w2l    = (__bf16*)(W + alloc((size_t)64 * 64 * sizeof(__bf16)));
    __bf16* w3h    = (__bf16*)(W + alloc((size_t)64 * 64 * sizeof(__bf16)));
    __bf16* w3l    = (__bf16*)(W + alloc((size_t)64 * 64 * sizeof(__bf16)));
    float*  gp     = (float*) (W + alloc((size_t)K1P * sizeof(float)));
    float*  bp     = (float*) (W + alloc((size_t)K1P * sizeof(float)));
    if (ws_size < o) return;   // (round-2 evidence: ws >= 265.6 MB; need ~264.9 MB)

    // weight prep
    prep_w<<<(64 * K1P + 255) / 256, 256, 0, stream>>>(w1, w1h, w1l, INDIM, K1P);
    prep_w<<<(64 * 64 + 255) / 256, 256, 0, stream>>>(w2, w2h, w2l, 64, 64);
    prep_w<<<(64 * 64 + 255) / 256, 256, 0, stream>>>(w3, w3h, w3l, 64, 64);
    prep_gb<<<1, 256, 0, stream>>>(gamma, beta, gp, bp);

    // counting sort: counts -> exclusive scan (in place) -> slot assignment
    hipMemsetAsync(off, 0, (size_t)NCNT * sizeof(int), stream);
    count_kernel<<<(ND + 255) / 256, 256, 0, stream>>>(qidx, off);
    scan1<<<NBLK_SCAN, 256, 0, stream>>>(off, bsum);
    scan2<<<1, 64, 0, stream>>>(bsum);
    scan3<<<NBLK_SCAN, 256, 0, stream>>>(off, bsum);
    fill_kernel<<<(ND + 255) / 256, 256, 0, stream>>>(qidx, off, slot_j, slot_k);

    // edge MLP (MFMA) -> sorted msg
    edge_mlp_mfma<<<ND / 64, 256, 0, stream>>>(x, pos, qidx, qattr, gp, bp,
                                               w1h, w1l, b1, w2h, w2l, b2,
                                               w3h, w3l, b3, slot_j, slot_k, msg);
    // node aggregation + w_out
    node_out<<<2048, 256, 0, stream>>>(msg, off, w_out, out);
}

// Round 4
// 752.442 us; speedup vs baseline: 2.6016x; 1.2351x over previous
//
#include <hip/hip_runtime.h>
#include <math.h>

#define NN 100000
#define ND 1000000
#define INDIM 133
#define K1P 160                 // padded input dim (5 x 32)
#define NCNT (2*NN)
#define SCAN_CHUNK 2048
#define NBLK_SCAN ((NCNT + SCAN_CHUNK - 1) / SCAN_CHUNK)
#define HS 72                   // LDS h-tile row stride in bf16 elems (144B: 2-way-bank-safe)

typedef __bf16 bf16x8 __attribute__((ext_vector_type(8)));
typedef float  f32x4  __attribute__((ext_vector_type(4)));
typedef _Float16 f16;

__device__ __forceinline__ f32x4 mfma_bf16(bf16x8 a, bf16x8 b, f32x4 c) {
    return __builtin_amdgcn_mfma_f32_16x16x32_bf16(a, b, c, 0, 0, 0);
}

__device__ __forceinline__ float3 f3sub(float3 a, float3 b) {
    return make_float3(a.x - b.x, a.y - b.y, a.z - b.z);
}
__device__ __forceinline__ float3 f3cross(float3 a, float3 b) {
    return make_float3(a.y * b.z - a.z * b.y, a.z * b.x - a.x * b.z, a.x * b.y - a.y * b.x);
}
__device__ __forceinline__ float f3dot(float3 a, float3 b) {
    return a.x * b.x + a.y * b.y + a.z * b.z;
}
__device__ __forceinline__ float3 f3load(const float* __restrict__ p, int idx) {
    const float* q = p + (size_t)idx * 3;
    return make_float3(q[0], q[1], q[2]);
}
__device__ __forceinline__ float fsilu(float v) {
    return v / (1.0f + __expf(-v));
}

// ---- weight prep: transpose to [n][k], pad K, split into bf16 hi+lo ----
__global__ __launch_bounds__(256) void prep_w(const float* __restrict__ w,
                                              __bf16* __restrict__ hi,
                                              __bf16* __restrict__ lo,
                                              int K, int KP) {
    int idx = blockIdx.x * 256 + threadIdx.x;
    if (idx >= 64 * KP) return;
    int n = idx / KP, kp = idx - n * KP;
    float v = (kp < K) ? w[(size_t)kp * 64 + n] : 0.0f;
    __bf16 h = (__bf16)v;
    hi[idx] = h;
    lo[idx] = (__bf16)(v - (float)h);
}

// ---- fold w_out into w3: W3'' = (w3 @ w_out) * 2^-4, b3'' = (b3 @ w_out) * 2^-4.
// Stored transposed [c][k], split hi/lo. Exact by linearity of segment-mean.
__global__ __launch_bounds__(256) void prep_w3(const float* __restrict__ w3,
                                               const float* __restrict__ b3,
                                               const float* __restrict__ wout,
                                               __bf16* __restrict__ hiT,
                                               __bf16* __restrict__ loT,
                                               float* __restrict__ b3f) {
    const int tid = threadIdx.x;
    for (int idx = tid; idx < 64 * 64; idx += 256) {
        int k = idx >> 6, c = idx & 63;
        float s = 0.0f;
        for (int q = 0; q < 64; ++q)
            s = fmaf(w3[(size_t)k * 64 + q], wout[(size_t)q * 64 + c], s);
        s *= 0.0625f;
        __bf16 h = (__bf16)s;
        hiT[(size_t)c * 64 + k] = h;
        loT[(size_t)c * 64 + k] = (__bf16)(s - (float)h);
    }
    if (tid < 64) {
        float s = 0.0f;
        for (int q = 0; q < 64; ++q)
            s = fmaf(b3[q], wout[(size_t)q * 64 + tid], s);
        b3f[tid] = s * 0.0625f;
    }
}

__global__ void prep_gb(const float* __restrict__ g, const float* __restrict__ b,
                        float* __restrict__ gp, float* __restrict__ bp) {
    int i = threadIdx.x;
    if (i < K1P) {
        gp[i] = (i < INDIM) ? g[i] : 0.0f;
        bp[i] = (i < INDIM) ? b[i] : 0.0f;
    }
}

// ---- counting sort machinery ----
__global__ __launch_bounds__(256) void count_kernel(const int* __restrict__ qidx,
                                                    int* __restrict__ cnt) {
    int e = blockIdx.x * 256 + threadIdx.x;
    if (e < ND) {
        atomicAdd(&cnt[qidx[ND + e]], 1);
        atomicAdd(&cnt[NN + qidx[2 * ND + e]], 1);
    }
}

__global__ __launch_bounds__(256) void scan1(int* data, int* __restrict__ bsum) {
    __shared__ int lds[256];
    const int tid = threadIdx.x;
    const int base = blockIdx.x * SCAN_CHUNK + tid * 8;
    int v[8];
    int tsum = 0;
#pragma unroll
    for (int t = 0; t < 8; ++t) {
        v[t] = (base + t < NCNT) ? data[base + t] : 0;
        tsum += v[t];
    }
    lds[tid] = tsum;
    __syncthreads();
    for (int d = 1; d < 256; d <<= 1) {
        int t = 0;
        if (tid >= d) t = lds[tid - d];
        __syncthreads();
        lds[tid] += t;
        __syncthreads();
    }
    if (tid == 255) bsum[blockIdx.x] = lds[255];
    int run = lds[tid] - tsum;
#pragma unroll
    for (int t = 0; t < 8; ++t) {
        if (base + t < NCNT) data[base + t] = run;
        run += v[t];
    }
}

__global__ void scan2(int* __restrict__ bsum) {
    if (threadIdx.x == 0 && blockIdx.x == 0) {
        int run = 0;
        for (int b = 0; b < NBLK_SCAN; ++b) {
            int t = bsum[b];
            bsum[b] = run;
            run += t;
        }
    }
}

__global__ __launch_bounds__(256) void scan3(int* __restrict__ off,
                                             const int* __restrict__ bsum) {
    const int base = blockIdx.x * SCAN_CHUNK + threadIdx.x * 8;
    const int add = bsum[blockIdx.x];
#pragma unroll
    for (int t = 0; t < 8; ++t) {
        int i = base + t;
        if (i < NCNT) off[i] += add;
    }
}

// fill: afterwards off[b] = END of bucket b (start = b==0 ? 0 : off[b-1])
__global__ __launch_bounds__(256) void fill_kernel(const int* __restrict__ qidx,
                                                   int* __restrict__ off,
                                                   int* __restrict__ slot_j,
                                                   int* __restrict__ slot_k) {
    int e = blockIdx.x * 256 + threadIdx.x;
    if (e < ND) {
        slot_j[e] = atomicAdd(&off[qidx[ND + e]], 1);
        slot_k[e] = atomicAdd(&off[NN + qidx[2 * ND + e]], 1);
    }
}

// ---- edge MLP: per-wave 32 edges (2 M-tiles sharing every B-fragment load),
// split-bf16 MFMA, no __syncthreads. w_out folded into layer 3. ----
__global__ __launch_bounds__(256) void edge_mlp_mfma(
    const float* __restrict__ x, const float* __restrict__ pos,
    const int* __restrict__ qidx, const float* __restrict__ qattr,
    const float* __restrict__ gp, const float* __restrict__ bp,
    const __bf16* __restrict__ w1h, const __bf16* __restrict__ w1l, const float* __restrict__ b1,
    const __bf16* __restrict__ w2h, const __bf16* __restrict__ w2l, const float* __restrict__ b2,
    const __bf16* __restrict__ w3h, const __bf16* __restrict__ w3l, const float* __restrict__ b3f,
    const int* __restrict__ slot_j, const int* __restrict__ slot_k,
    f16* __restrict__ msg)
{
    __shared__ __align__(16) __bf16 hsh[4][2][16 * HS];
    __shared__ __align__(16) __bf16 hsl[4][2][16 * HS];

    const int tid = threadIdx.x;
    const int w   = tid >> 6;
    const int l   = tid & 63;
    const int m   = l & 15;
    const int kg  = l >> 4;
    const int ebase = (blockIdx.x * 4 + w) * 32;
    if (ebase >= ND) return;               // no barriers in kernel: early-out safe

    bf16x8 ah[2][5], al[2][5];

#pragma unroll
    for (int t = 0; t < 2; ++t) {
        const int e  = ebase + 16 * t + m;
        const int i_ = qidx[e];
        const int l_ = qidx[3 * ND + e];

        // dihedral + attrs only on kg==0 lanes (their af[4] slice holds cols 128..135)
        float cosd = 0.f, sind = 0.f, at0 = 0.f, at1 = 0.f, at2 = 0.f;
        if (kg == 0) {
            const int j_ = qidx[ND + e];
            const int k_ = qidx[2 * ND + e];
            float3 pi = f3load(pos, i_), pj = f3load(pos, j_);
            float3 pk = f3load(pos, k_), pl = f3load(pos, l_);
            float3 d1 = f3sub(pj, pi);
            float3 d2 = f3sub(pk, pj);
            float3 d3 = f3sub(pl, pk);
            float3 n1 = f3cross(d1, d2);
            float3 n2 = f3cross(d2, d3);
            float r1 = 1.0f / fmaxf(sqrtf(f3dot(n1, n1)), 1e-6f);
            n1.x *= r1; n1.y *= r1; n1.z *= r1;
            float r2 = 1.0f / fmaxf(sqrtf(f3dot(n2, n2)), 1e-6f);
            n2.x *= r2; n2.y *= r2; n2.z *= r2;
            cosd = fminf(fmaxf(f3dot(n1, n2), -1.0f), 1.0f);
            float rb = 1.0f / fmaxf(sqrtf(f3dot(d2, d2)), 1e-6f);
            float3 b2n = make_float3(d2.x * rb, d2.y * rb, d2.z * rb);
            float3 mm = f3cross(n1, b2n);
            sind = f3dot(mm, n2);
            at0 = qattr[(size_t)e * 3 + 0];
            at1 = qattr[(size_t)e * 3 + 1];
            at2 = qattr[(size_t)e * 3 + 2];
        }

        // gather this lane's k-slices of inp row m: cols 32s+8kg .. +7
        float af[5][8] __attribute__((aligned(16)));
        {
            const float* xi = x + (size_t)i_ * 64 + 8 * kg;
            const float* xl = x + (size_t)l_ * 64 + 8 * kg;
            *(float4*)&af[0][0] = *(const float4*)(xi);
            *(float4*)&af[0][4] = *(const float4*)(xi + 4);
            *(float4*)&af[1][0] = *(const float4*)(xi + 32);
            *(float4*)&af[1][4] = *(const float4*)(xi + 36);
            *(float4*)&af[2][0] = *(const float4*)(xl);
            *(float4*)&af[2][4] = *(const float4*)(xl + 4);
            *(float4*)&af[3][0] = *(const float4*)(xl + 32);
            *(float4*)&af[3][4] = *(const float4*)(xl + 36);
            af[4][0] = at0; af[4][1] = at1; af[4][2] = at2;
            af[4][3] = cosd; af[4][4] = sind;
            af[4][5] = 0.0f; af[4][6] = 0.0f; af[4][7] = 0.0f;
        }

        // LayerNorm over 133 via 4-lane butterfly (lanes m, m+16, m+32, m+48)
        float s1 = 0.0f, s2 = 0.0f;
#pragma unroll
        for (int s = 0; s < 5; ++s)
#pragma unroll
            for (int j = 0; j < 8; ++j) {
                float v = af[s][j];
                s1 += v;
                s2 = fmaf(v, v, s2);
            }
        s1 += __shfl_xor(s1, 16); s1 += __shfl_xor(s1, 32);
        s2 += __shfl_xor(s2, 16); s2 += __shfl_xor(s2, 32);
        const float mu  = s1 * (1.0f / INDIM);
        const float var = s2 * (1.0f / INDIM) - mu * mu;
        const float rs  = rsqrtf(fmaxf(var, 0.0f) + 1e-5f);

        // normalize + hi/lo bf16 split (padded cols: gamma=beta=0 -> exact 0)
#pragma unroll
        for (int s = 0; s < 5; ++s) {
            const float* gpp = gp + 32 * s + 8 * kg;
            const float* bpp = bp + 32 * s + 8 * kg;
#pragma unroll
            for (int j = 0; j < 8; ++j) {
                float v = (af[s][j] - mu) * rs * gpp[j] + bpp[j];
                __bf16 h = (__bf16)v;
                ah[t][s][j] = h;
                al[t][s][j] = (__bf16)(v - (float)h);
            }
        }
    }

    // ---- layer 1: each B-frag pair loaded once, used by both M-tiles ----
    f32x4 acc[2][4];
#pragma unroll
    for (int t = 0; t < 2; ++t)
#pragma unroll
        for (int nt = 0; nt < 4; ++nt) acc[t][nt] = (f32x4){0.f, 0.f, 0.f, 0.f};
#pragma unroll
    for (int s = 0; s < 5; ++s) {
#pragma unroll
        for (int nt = 0; nt < 4; ++nt) {
            const size_t wb = (size_t)(16 * nt + m) * K1P + 32 * s + 8 * kg;
            bf16x8 bh = *(const bf16x8*)(w1h + wb);
            bf16x8 bl = *(const bf16x8*)(w1l + wb);
            acc[0][nt] = mfma_bf16(ah[0][s], bh, acc[0][nt]);
            acc[0][nt] = mfma_bf16(al[0][s], bh, acc[0][nt]);
            acc[0][nt] = mfma_bf16(ah[0][s], bl, acc[0][nt]);
            acc[1][nt] = mfma_bf16(ah[1][s], bh, acc[1][nt]);
            acc[1][nt] = mfma_bf16(al[1][s], bh, acc[1][nt]);
            acc[1][nt] = mfma_bf16(ah[1][s], bl, acc[1][nt]);
        }
    }

    // bias + silu + h1 -> per-wave LDS tiles (C layout: row=4kg+r, col=16nt+m)
#pragma unroll
    for (int t = 0; t < 2; ++t) {
        __bf16* hhw = &hsh[w][t][0];
        __bf16* hlw = &hsl[w][t][0];
#pragma unroll
        for (int nt = 0; nt < 4; ++nt) {
            float bb = b1[16 * nt + m];
#pragma unroll
            for (int r = 0; r < 4; ++r) {
                float hv = fsilu(acc[t][nt][r] + bb);
                __bf16 h = (__bf16)hv;
                int o = (4 * kg + r) * HS + 16 * nt + m;
                hhw[o] = h;
                hlw[o] = (__bf16)(hv - (float)h);
            }
        }
    }

    // ---- layer 2 (same-wave DS ordering: no barrier) ----
    bf16x8 a2h[2][2], a2l[2][2];
#pragma unroll
    for (int t = 0; t < 2; ++t)
#pragma unroll
        for (int s = 0; s < 2; ++s) {
            a2h[t][s] = *(const bf16x8*)(&hsh[w][t][m * HS + 32 * s + 8 * kg]);
            a2l[t][s] = *(const bf16x8*)(&hsl[w][t][m * HS + 32 * s + 8 * kg]);
        }
    f32x4 acc2[2][4];
#pragma unroll
    for (int t = 0; t < 2; ++t)
#pragma unroll
        for (int nt = 0; nt < 4; ++nt) acc2[t][nt] = (f32x4){0.f, 0.f, 0.f, 0.f};
#pragma unroll
    for (int s = 0; s < 2; ++s) {
#pragma unroll
        for (int nt = 0; nt < 4; ++nt) {
            const size_t wb = (size_t)(16 * nt + m) * 64 + 32 * s + 8 * kg;
            bf16x8 bh = *(const bf16x8*)(w2h + wb);
            bf16x8 bl = *(const bf16x8*)(w2l + wb);
            acc2[0][nt] = mfma_bf16(a2h[0][s], bh, acc2[0][nt]);
            acc2[0][nt] = mfma_bf16(a2l[0][s], bh, acc2[0][nt]);
            acc2[0][nt] = mfma_bf16(a2h[0][s], bl, acc2[0][nt]);
            acc2[1][nt] = mfma_bf16(a2h[1][s], bh, acc2[1][nt]);
            acc2[1][nt] = mfma_bf16(a2l[1][s], bh, acc2[1][nt]);
            acc2[1][nt] = mfma_bf16(a2h[1][s], bl, acc2[1][nt]);
        }
    }
#pragma unroll
    for (int t = 0; t < 2; ++t) {
        __bf16* hhw = &hsh[w][t][0];
        __bf16* hlw = &hsl[w][t][0];
#pragma unroll
        for (int nt = 0; nt < 4; ++nt) {
            float bb = b2[16 * nt + m];
#pragma unroll
            for (int r = 0; r < 4; ++r) {
                float hv = fsilu(acc2[t][nt][r] + bb);
                __bf16 h = (__bf16)hv;
                int o = (4 * kg + r) * HS + 16 * nt + m;
                hhw[o] = h;
                hlw[o] = (__bf16)(hv - (float)h);
            }
        }
    }

    // ---- layer 3 (w_out + 2^-4 folded into weights) ----
    bf16x8 a3h[2][2], a3l[2][2];
#pragma unroll
    for (int t = 0; t < 2; ++t)
#pragma unroll
        for (int s = 0; s < 2; ++s) {
            a3h[t][s] = *(const bf16x8*)(&hsh[w][t][m * HS + 32 * s + 8 * kg]);
            a3l[t][s] = *(const bf16x8*)(&hsl[w][t][m * HS + 32 * s + 8 * kg]);
        }
    f32x4 acc3[2][4];
#pragma unroll
    for (int t = 0; t < 2; ++t)
#pragma unroll
        for (int nt = 0; nt < 4; ++nt) acc3[t][nt] = (f32x4){0.f, 0.f, 0.f, 0.f};
#pragma unroll
    for (int s = 0; s < 2; ++s) {
#pragma unroll
        for (int nt = 0; nt < 4; ++nt) {
            const size_t wb = (size_t)(16 * nt + m) * 64 + 32 * s + 8 * kg;
            bf16x8 bh = *(const bf16x8*)(w3h + wb);
            bf16x8 bl = *(const bf16x8*)(w3l + wb);
            acc3[0][nt] = mfma_bf16(a3h[0][s], bh, acc3[0][nt]);
            acc3[0][nt] = mfma_bf16(a3l[0][s], bh, acc3[0][nt]);
            acc3[0][nt] = mfma_bf16(a3h[0][s], bl, acc3[0][nt]);
            acc3[1][nt] = mfma_bf16(a3h[1][s], bh, acc3[1][nt]);
            acc3[1][nt] = mfma_bf16(a3l[1][s], bh, acc3[1][nt]);
            acc3[1][nt] = mfma_bf16(a3h[1][s], bl, acc3[1][nt]);
        }
    }

    // ---- msg: f16 rows to both sorted slot positions ----
    float b3v[4];
#pragma unroll
    for (int nt = 0; nt < 4; ++nt) b3v[nt] = b3f[16 * nt + m];
#pragma unroll
    for (int t = 0; t < 2; ++t) {
#pragma unroll
        for (int r = 0; r < 4; ++r) {
            int er = ebase + 16 * t + 4 * kg + r;
            size_t sj = (size_t)slot_j[er] * 64 + m;
            size_t sk = (size_t)slot_k[er] * 64 + m;
#pragma unroll
            for (int nt = 0; nt < 4; ++nt) {
                f16 hv = (f16)(acc3[t][nt][r] + b3v[nt]);
                msg[sj + 16 * nt] = hv;
                msg[sk + 16 * nt] = hv;
            }
        }
    }
}

// ---- node aggregation: pure streaming segmented mean (w_out already folded) ----
__global__ __launch_bounds__(256) void node_out(const f16* __restrict__ msg,
                                                const int* __restrict__ off,
                                                float* __restrict__ out) {
    const int w = threadIdx.x >> 6;
    const int lane = threadIdx.x & 63;
    for (int n = blockIdx.x * 4 + w; n < NN; n += gridDim.x * 4) {
        int ja = (n == 0) ? 0 : off[n - 1];
        int jb = off[n];
        int ka = off[NN + n - 1];   // n==0 -> off[NN-1] = start of k-region
        int kb = off[NN + n];
        float sj = 0.0f;
        for (int p = ja; p < jb; ++p) sj += (float)msg[(size_t)p * 64 + lane];
        float sk = 0.0f;
        for (int p = ka; p < kb; ++p) sk += (float)msg[(size_t)p * 64 + lane];
        out[(size_t)n * 64 + lane] = sj / fmaxf((float)(jb - ja), 1.0f) +
                                     sk / fmaxf((float)(kb - ka), 1.0f);
    }
}

// ============================ launch ============================

extern "C" void kernel_launch(void* const* d_in, const int* in_sizes, int n_in,
                              void* d_out, int out_size, void* d_ws, size_t ws_size,
                              hipStream_t stream) {
    (void)in_sizes; (void)n_in; (void)out_size;

    const float* x     = (const float*)d_in[0];
    const float* pos   = (const float*)d_in[1];
    const int*   qidx  = (const int*)d_in[2];
    const float* qattr = (const float*)d_in[3];
    const float* gamma = (const float*)d_in[4];
    const float* beta  = (const float*)d_in[5];
    const float* w1    = (const float*)d_in[6];
    const float* b1    = (const float*)d_in[7];
    const float* w2    = (const float*)d_in[8];
    const float* b2    = (const float*)d_in[9];
    const float* w3    = (const float*)d_in[10];
    const float* b3    = (const float*)d_in[11];
    const float* w_out = (const float*)d_in[12];
    float* out = (float*)d_out;

    size_t o = 0;
    auto alloc = [&](size_t bytes) { size_t r = o; o = (o + bytes + 255) & ~(size_t)255; return r; };
    char* W = (char*)d_ws;
    f16*    msg    = (f16*)   (W + alloc((size_t)2 * ND * 64 * sizeof(f16)));
    int*    slot_j = (int*)   (W + alloc((size_t)ND * sizeof(int)));
    int*    slot_k = (int*)   (W + alloc((size_t)ND * sizeof(int)));
    int*    off    = (int*)   (W + alloc((size_t)NCNT * sizeof(int)));
    int*    bsum   = (int*)   (W + alloc((size_t)NBLK_SCAN * sizeof(int)));
    __bf16* w1h    = (__bf16*)(W + alloc((size_t)64 * K1P * sizeof(__bf16)));
    __bf16* w1l    = (__bf16*)(W + alloc((size_t)64 * K1P * sizeof(__bf16)));
    __bf16* w2h    = (__bf16*)(W + alloc((size_t)64 * 64 * sizeof(__bf16)));
    __bf16* w2l    = (__bf16*)(W + alloc((size_t)64 * 64 * sizeof(__bf16)));
    __bf16* w3h    = (__bf16*)(W + alloc((size_t)64 * 64 * sizeof(__bf16)));
    __bf16* w3l    = (__bf16*)(W + alloc((size_t)64 * 64 * sizeof(__bf16)));
    float*  gp     = (float*) (W + alloc((size_t)K1P * sizeof(float)));
    float*  bp     = (float*) (W + alloc((size_t)K1P * sizeof(float)));
    float*  b3f    = (float*) (W + alloc((size_t)64 * sizeof(float)));
    if (ws_size < o) return;

    // weight prep (w3 folded with w_out and the 0.5*0.125 scale)
    prep_w<<<(64 * K1P + 255) / 256, 256, 0, stream>>>(w1, w1h, w1l, INDIM, K1P);
    prep_w<<<(64 * 64 + 255) / 256, 256, 0, stream>>>(w2, w2h, w2l, 64, 64);
    prep_w3<<<1, 256, 0, stream>>>(w3, b3, w_out, w3h, w3l, b3f);
    prep_gb<<<1, 256, 0, stream>>>(gamma, beta, gp, bp);

    // counting sort
    hipMemsetAsync(off, 0, (size_t)NCNT * sizeof(int), stream);
    count_kernel<<<(ND + 255) / 256, 256, 0, stream>>>(qidx, off);
    scan1<<<NBLK_SCAN, 256, 0, stream>>>(off, bsum);
    scan2<<<1, 64, 0, stream>>>(bsum);
    scan3<<<NBLK_SCAN, 256, 0, stream>>>(off, bsum);
    fill_kernel<<<(ND + 255) / 256, 256, 0, stream>>>(qidx, off, slot_j, slot_k);

    // edge MLP (MFMA, 32 edges/wave) -> sorted msg (w_out folded)
    edge_mlp_mfma<<<(ND + 127) / 128, 256, 0, stream>>>(x, pos, qidx, qattr, gp, bp,
                                                        w1h, w1l, b1, w2h, w2l, b2,
                                                        w3h, w3l, b3f, slot_j, slot_k, msg);
    // node aggregation (pure segmented mean)
    node_out<<<4096, 256, 0, stream>>>(msg, off, out);
}

// Round 5
// 626.496 us; speedup vs baseline: 3.1247x; 1.2010x over previous
//
#include <hip/hip_runtime.h>
#include <math.h>

#define NN 100000
#define ND 1000000
#define INDIM 133
#define K1P 160                 // padded input dim (5 x 32)
#define NCNT (2*NN)
#define SCAN_CHUNK 2048
#define NBLK_SCAN ((NCNT + SCAN_CHUNK - 1) / SCAN_CHUNK)
#define HS 72                   // LDS h-tile row stride in bf16 elems (144B)

typedef __bf16 bf16x8 __attribute__((ext_vector_type(8)));
typedef __bf16 bf16x4 __attribute__((ext_vector_type(4)));
typedef float  f32x4  __attribute__((ext_vector_type(4)));
typedef _Float16 f16;
typedef _Float16 f16x4 __attribute__((ext_vector_type(4)));

__device__ __forceinline__ f32x4 mfma_bf16(bf16x8 a, bf16x8 b, f32x4 c) {
    return __builtin_amdgcn_mfma_f32_16x16x32_bf16(a, b, c, 0, 0, 0);
}

__device__ __forceinline__ float3 f3sub(float3 a, float3 b) {
    return make_float3(a.x - b.x, a.y - b.y, a.z - b.z);
}
__device__ __forceinline__ float3 f3cross(float3 a, float3 b) {
    return make_float3(a.y * b.z - a.z * b.y, a.z * b.x - a.x * b.z, a.x * b.y - a.y * b.x);
}
__device__ __forceinline__ float f3dot(float3 a, float3 b) {
    return a.x * b.x + a.y * b.y + a.z * b.z;
}
__device__ __forceinline__ float3 f3load(const float* __restrict__ p, int idx) {
    const float* q = p + (size_t)idx * 3;
    return make_float3(q[0], q[1], q[2]);
}
__device__ __forceinline__ float fsilu(float v) {
    return v / (1.0f + __expf(-v));
}

// ---- weight prep: transpose to [n][k], pad K, split into bf16 hi+lo.
// permute!=0: k index is in PERMUTED h-space (k' = 4m+nt <-> orig k = 16nt+m).
__global__ __launch_bounds__(256) void prep_w(const float* __restrict__ w,
                                              __bf16* __restrict__ hi,
                                              __bf16* __restrict__ lo,
                                              int K, int KP, int permute) {
    int idx = blockIdx.x * 256 + threadIdx.x;
    if (idx >= 64 * KP) return;
    int n = idx / KP, kp = idx - n * KP;
    int ko = permute ? (16 * (kp & 3) + (kp >> 2)) : kp;
    float v = (ko < K) ? w[(size_t)ko * 64 + n] : 0.0f;
    __bf16 h = (__bf16)v;
    hi[idx] = h;
    lo[idx] = (__bf16)(v - (float)h);
}

// ---- fold w_out into w3: W3'' = (w3 @ w_out) * 2^-4, b3'' = (b3 @ w_out) * 2^-4.
// Stored transposed [c][k'] with k' the PERMUTED h2-column index.
__global__ __launch_bounds__(256) void prep_w3(const float* __restrict__ w3,
                                               const float* __restrict__ b3,
                                               const float* __restrict__ wout,
                                               __bf16* __restrict__ hiT,
                                               __bf16* __restrict__ loT,
                                               float* __restrict__ b3f) {
    const int tid = threadIdx.x;
    for (int idx = tid; idx < 64 * 64; idx += 256) {
        int k = idx >> 6, c = idx & 63;
        float s = 0.0f;
        for (int q = 0; q < 64; ++q)
            s = fmaf(w3[(size_t)k * 64 + q], wout[(size_t)q * 64 + c], s);
        s *= 0.0625f;
        __bf16 h = (__bf16)s;
        int kp = 4 * (k & 15) + (k >> 4);   // permuted k position
        hiT[(size_t)c * 64 + kp] = h;
        loT[(size_t)c * 64 + kp] = (__bf16)(s - (float)h);
    }
    if (tid < 64) {
        float s = 0.0f;
        for (int q = 0; q < 64; ++q)
            s = fmaf(b3[q], wout[(size_t)q * 64 + tid], s);
        b3f[tid] = s * 0.0625f;
    }
}

__global__ void prep_gb(const float* __restrict__ g, const float* __restrict__ b,
                        float* __restrict__ gp, float* __restrict__ bp) {
    int i = threadIdx.x;
    if (i < K1P) {
        gp[i] = (i < INDIM) ? g[i] : 0.0f;
        bp[i] = (i < INDIM) ? b[i] : 0.0f;
    }
}

// ---- counting sort machinery ----
__global__ __launch_bounds__(256) void count_kernel(const int* __restrict__ qidx,
                                                    int* __restrict__ cnt) {
    int e = blockIdx.x * 256 + threadIdx.x;
    if (e < ND) {
        atomicAdd(&cnt[qidx[ND + e]], 1);
        atomicAdd(&cnt[NN + qidx[2 * ND + e]], 1);
    }
}

__global__ __launch_bounds__(256) void scan1(int* data, int* __restrict__ bsum) {
    __shared__ int lds[256];
    const int tid = threadIdx.x;
    const int base = blockIdx.x * SCAN_CHUNK + tid * 8;
    int v[8];
    int tsum = 0;
#pragma unroll
    for (int t = 0; t < 8; ++t) {
        v[t] = (base + t < NCNT) ? data[base + t] : 0;
        tsum += v[t];
    }
    lds[tid] = tsum;
    __syncthreads();
    for (int d = 1; d < 256; d <<= 1) {
        int t = 0;
        if (tid >= d) t = lds[tid - d];
        __syncthreads();
        lds[tid] += t;
        __syncthreads();
    }
    if (tid == 255) bsum[blockIdx.x] = lds[255];
    int run = lds[tid] - tsum;
#pragma unroll
    for (int t = 0; t < 8; ++t) {
        if (base + t < NCNT) data[base + t] = run;
        run += v[t];
    }
}

// parallel exclusive scan over NBLK_SCAN (<=128) block sums
__global__ __launch_bounds__(128) void scan2(int* __restrict__ bsum) {
    __shared__ int lds[128];
    const int t = threadIdx.x;
    int v = (t < NBLK_SCAN) ? bsum[t] : 0;
    lds[t] = v;
    __syncthreads();
    for (int d = 1; d < 128; d <<= 1) {
        int u = (t >= d) ? lds[t - d] : 0;
        __syncthreads();
        lds[t] += u;
        __syncthreads();
    }
    if (t < NBLK_SCAN) bsum[t] = lds[t] - v;
}

__global__ __launch_bounds__(256) void scan3(int* __restrict__ off,
                                             const int* __restrict__ bsum) {
    const int base = blockIdx.x * SCAN_CHUNK + threadIdx.x * 8;
    const int add = bsum[blockIdx.x];
#pragma unroll
    for (int t = 0; t < 8; ++t) {
        int i = base + t;
        if (i < NCNT) off[i] += add;
    }
}

// fill: afterwards off[b] = END of bucket b (start = b==0 ? 0 : off[b-1])
__global__ __launch_bounds__(256) void fill_kernel(const int* __restrict__ qidx,
                                                   int* __restrict__ off,
                                                   int* __restrict__ slot_j,
                                                   int* __restrict__ slot_k) {
    int e = blockIdx.x * 256 + threadIdx.x;
    if (e < ND) {
        slot_j[e] = atomicAdd(&off[qidx[ND + e]], 1);
        slot_k[e] = atomicAdd(&off[NN + qidx[2 * ND + e]], 1);
    }
}

// ---- edge MLP: 32 edges/wave, split-bf16 layer1, hi-only h for layers 2/3,
// permuted h/msg column layout (col' = 4m+nt), no __syncthreads. ----
__global__ __launch_bounds__(256) void edge_mlp_mfma(
    const float* __restrict__ x, const float* __restrict__ pos,
    const int* __restrict__ qidx, const float* __restrict__ qattr,
    const float* __restrict__ gp, const float* __restrict__ bp,
    const __bf16* __restrict__ w1h, const __bf16* __restrict__ w1l, const float* __restrict__ b1,
    const __bf16* __restrict__ w2h, const __bf16* __restrict__ w2l, const float* __restrict__ b2,
    const __bf16* __restrict__ w3h, const __bf16* __restrict__ w3l, const float* __restrict__ b3f,
    const int* __restrict__ slot_j, const int* __restrict__ slot_k,
    f16* __restrict__ msg)
{
    __shared__ __align__(16) __bf16 hsh[4][2][16 * HS];

    const int tid = threadIdx.x;
    const int w   = tid >> 6;
    const int l   = tid & 63;
    const int m   = l & 15;
    const int kg  = l >> 4;
    const int ebase = (blockIdx.x * 4 + w) * 32;
    if (ebase >= ND) return;               // no barriers: early-out safe

    // ---- dihedral for both tiles concurrently: tile kg on lanes kg<2 ----
    float cosd = 0.f, sind = 0.f, at0 = 0.f, at1 = 0.f, at2 = 0.f;
    if (kg < 2) {
        const int e2 = ebase + 16 * kg + m;
        const int i2 = qidx[e2];
        const int j2 = qidx[ND + e2];
        const int k2 = qidx[2 * ND + e2];
        const int l2 = qidx[3 * ND + e2];
        float3 pi = f3load(pos, i2), pj = f3load(pos, j2);
        float3 pk = f3load(pos, k2), pl = f3load(pos, l2);
        float3 d1 = f3sub(pj, pi);
        float3 d2 = f3sub(pk, pj);
        float3 d3 = f3sub(pl, pk);
        float3 n1 = f3cross(d1, d2);
        float3 n2 = f3cross(d2, d3);
        float r1 = 1.0f / fmaxf(sqrtf(f3dot(n1, n1)), 1e-6f);
        n1.x *= r1; n1.y *= r1; n1.z *= r1;
        float r2 = 1.0f / fmaxf(sqrtf(f3dot(n2, n2)), 1e-6f);
        n2.x *= r2; n2.y *= r2; n2.z *= r2;
        cosd = fminf(fmaxf(f3dot(n1, n2), -1.0f), 1.0f);
        float rb = 1.0f / fmaxf(sqrtf(f3dot(d2, d2)), 1e-6f);
        float3 b2n = make_float3(d2.x * rb, d2.y * rb, d2.z * rb);
        float3 mm = f3cross(n1, b2n);
        sind = f3dot(mm, n2);
        at0 = qattr[(size_t)e2 * 3 + 0];
        at1 = qattr[(size_t)e2 * 3 + 1];
        at2 = qattr[(size_t)e2 * 3 + 2];
    }

    bf16x8 ah[2][5], al[2][5];

#pragma unroll
    for (int t = 0; t < 2; ++t) {
        const int e  = ebase + 16 * t + m;
        const int i_ = qidx[e];
        const int l_ = qidx[3 * ND + e];

        // pull this tile's dihedral scalars from lanes kg==t
        float c_t = __shfl(cosd, m + 16 * t);
        float s_t = __shfl(sind, m + 16 * t);
        float a0t = __shfl(at0, m + 16 * t);
        float a1t = __shfl(at1, m + 16 * t);
        float a2t = __shfl(at2, m + 16 * t);

        // gather this lane's k-slices of inp row m: cols 32s+8kg .. +7
        float af[5][8] __attribute__((aligned(16)));
        {
            const float* xi = x + (size_t)i_ * 64 + 8 * kg;
            const float* xl = x + (size_t)l_ * 64 + 8 * kg;
            *(float4*)&af[0][0] = *(const float4*)(xi);
            *(float4*)&af[0][4] = *(const float4*)(xi + 4);
            *(float4*)&af[1][0] = *(const float4*)(xi + 32);
            *(float4*)&af[1][4] = *(const float4*)(xi + 36);
            *(float4*)&af[2][0] = *(const float4*)(xl);
            *(float4*)&af[2][4] = *(const float4*)(xl + 4);
            *(float4*)&af[3][0] = *(const float4*)(xl + 32);
            *(float4*)&af[3][4] = *(const float4*)(xl + 36);
            float g0 = (kg == 0) ? 1.0f : 0.0f;   // cols 128-132 live in kg==0's s=4 slice
            af[4][0] = a0t * g0;
            af[4][1] = a1t * g0;
            af[4][2] = a2t * g0;
            af[4][3] = c_t * g0;
            af[4][4] = s_t * g0;
            af[4][5] = 0.0f; af[4][6] = 0.0f; af[4][7] = 0.0f;
        }

        // LayerNorm over 133 via 4-lane butterfly (lanes m, m+16, m+32, m+48)
        float s1 = 0.0f, s2 = 0.0f;
#pragma unroll
        for (int s = 0; s < 5; ++s)
#pragma unroll
            for (int j = 0; j < 8; ++j) {
                float v = af[s][j];
                s1 += v;
                s2 = fmaf(v, v, s2);
            }
        s1 += __shfl_xor(s1, 16); s1 += __shfl_xor(s1, 32);
        s2 += __shfl_xor(s2, 16); s2 += __shfl_xor(s2, 32);
        const float mu  = s1 * (1.0f / INDIM);
        const float var = s2 * (1.0f / INDIM) - mu * mu;
        const float rs  = rsqrtf(fmaxf(var, 0.0f) + 1e-5f);

        // normalize + hi/lo bf16 split (padded cols: gamma=beta=0 -> exact 0)
#pragma unroll
        for (int s = 0; s < 5; ++s) {
            const float* gpp = gp + 32 * s + 8 * kg;
            const float* bpp = bp + 32 * s + 8 * kg;
#pragma unroll
            for (int j = 0; j < 8; ++j) {
                float v = (af[s][j] - mu) * rs * gpp[j] + bpp[j];
                __bf16 h = (__bf16)v;
                ah[t][s][j] = h;
                al[t][s][j] = (__bf16)(v - (float)h);
            }
        }
    }

    float b1v[4], b2v[4], b3v[4];
#pragma unroll
    for (int nt = 0; nt < 4; ++nt) {
        b1v[nt] = b1[16 * nt + m];
        b2v[nt] = b2[16 * nt + m];
        b3v[nt] = b3f[16 * nt + m];
    }

    // ---- layer 1: full split (3 MFMA), each B-frag shared by both M-tiles ----
    f32x4 acc[2][4];
#pragma unroll
    for (int t = 0; t < 2; ++t)
#pragma unroll
        for (int nt = 0; nt < 4; ++nt) acc[t][nt] = (f32x4){0.f, 0.f, 0.f, 0.f};
#pragma unroll
    for (int s = 0; s < 5; ++s) {
#pragma unroll
        for (int nt = 0; nt < 4; ++nt) {
            const size_t wb = (size_t)(16 * nt + m) * K1P + 32 * s + 8 * kg;
            bf16x8 bh = *(const bf16x8*)(w1h + wb);
            bf16x8 bl = *(const bf16x8*)(w1l + wb);
            acc[0][nt] = mfma_bf16(ah[0][s], bh, acc[0][nt]);
            acc[0][nt] = mfma_bf16(al[0][s], bh, acc[0][nt]);
            acc[0][nt] = mfma_bf16(ah[0][s], bl, acc[0][nt]);
            acc[1][nt] = mfma_bf16(ah[1][s], bh, acc[1][nt]);
            acc[1][nt] = mfma_bf16(al[1][s], bh, acc[1][nt]);
            acc[1][nt] = mfma_bf16(ah[1][s], bl, acc[1][nt]);
        }
    }

    // bias + silu + h1 -> LDS (hi only, PERMUTED cols: col' = 4m+nt, 8B stores)
#pragma unroll
    for (int t = 0; t < 2; ++t) {
        __bf16* hhw = &hsh[w][t][0];
#pragma unroll
        for (int r = 0; r < 4; ++r) {
            bf16x4 hv4;
#pragma unroll
            for (int nt = 0; nt < 4; ++nt)
                hv4[nt] = (__bf16)fsilu(acc[t][nt][r] + b1v[nt]);
            *(bf16x4*)(hhw + (4 * kg + r) * HS + m * 4) = hv4;
        }
    }

    // ---- layer 2: hi-A x split-W (2 MFMA per (s,nt)) ----
    bf16x8 a2h[2][2];
#pragma unroll
    for (int t = 0; t < 2; ++t)
#pragma unroll
        for (int s = 0; s < 2; ++s)
            a2h[t][s] = *(const bf16x8*)(&hsh[w][t][m * HS + 32 * s + 8 * kg]);
    f32x4 acc2[2][4];
#pragma unroll
    for (int t = 0; t < 2; ++t)
#pragma unroll
        for (int nt = 0; nt < 4; ++nt) acc2[t][nt] = (f32x4){0.f, 0.f, 0.f, 0.f};
#pragma unroll
    for (int s = 0; s < 2; ++s) {
#pragma unroll
        for (int nt = 0; nt < 4; ++nt) {
            const size_t wb = (size_t)(16 * nt + m) * 64 + 32 * s + 8 * kg;
            bf16x8 bh = *(const bf16x8*)(w2h + wb);
            bf16x8 bl = *(const bf16x8*)(w2l + wb);
            acc2[0][nt] = mfma_bf16(a2h[0][s], bh, acc2[0][nt]);
            acc2[0][nt] = mfma_bf16(a2h[0][s], bl, acc2[0][nt]);
            acc2[1][nt] = mfma_bf16(a2h[1][s], bh, acc2[1][nt]);
            acc2[1][nt] = mfma_bf16(a2h[1][s], bl, acc2[1][nt]);
        }
    }
#pragma unroll
    for (int t = 0; t < 2; ++t) {
        __bf16* hhw = &hsh[w][t][0];
#pragma unroll
        for (int r = 0; r < 4; ++r) {
            bf16x4 hv4;
#pragma unroll
            for (int nt = 0; nt < 4; ++nt)
                hv4[nt] = (__bf16)fsilu(acc2[t][nt][r] + b2v[nt]);
            *(bf16x4*)(hhw + (4 * kg + r) * HS + m * 4) = hv4;
        }
    }

    // ---- layer 3 (w_out + 2^-4 folded) ----
    bf16x8 a3h[2][2];
#pragma unroll
    for (int t = 0; t < 2; ++t)
#pragma unroll
        for (int s = 0; s < 2; ++s)
            a3h[t][s] = *(const bf16x8*)(&hsh[w][t][m * HS + 32 * s + 8 * kg]);
    f32x4 acc3[2][4];
#pragma unroll
    for (int t = 0; t < 2; ++t)
#pragma unroll
        for (int nt = 0; nt < 4; ++nt) acc3[t][nt] = (f32x4){0.f, 0.f, 0.f, 0.f};
#pragma unroll
    for (int s = 0; s < 2; ++s) {
#pragma unroll
        for (int nt = 0; nt < 4; ++nt) {
            const size_t wb = (size_t)(16 * nt + m) * 64 + 32 * s + 8 * kg;
            bf16x8 bh = *(const bf16x8*)(w3h + wb);
            bf16x8 bl = *(const bf16x8*)(w3l + wb);
            acc3[0][nt] = mfma_bf16(a3h[0][s], bh, acc3[0][nt]);
            acc3[0][nt] = mfma_bf16(a3h[0][s], bl, acc3[0][nt]);
            acc3[1][nt] = mfma_bf16(a3h[1][s], bh, acc3[1][nt]);
            acc3[1][nt] = mfma_bf16(a3h[1][s], bl, acc3[1][nt]);
        }
    }

    // ---- msg: permuted-col f16x4 (8B) stores to both sorted slots ----
#pragma unroll
    for (int t = 0; t < 2; ++t) {
#pragma unroll
        for (int r = 0; r < 4; ++r) {
            f16x4 v;
#pragma unroll
            for (int nt = 0; nt < 4; ++nt)
                v[nt] = (f16)(acc3[t][nt][r] + b3v[nt]);
            const int er = ebase + 16 * t + 4 * kg + r;
            *(f16x4*)(msg + (size_t)slot_j[er] * 64 + m * 4) = v;
            *(f16x4*)(msg + (size_t)slot_k[er] * 64 + m * 4) = v;
        }
    }
}

// ---- node aggregation: 4 rows (512B) per wave-load, shfl reduce, permuted cols ----
__global__ __launch_bounds__(256) void node_out(const f16* __restrict__ msg,
                                                const int* __restrict__ off,
                                                float* __restrict__ out) {
    const int w   = threadIdx.x >> 6;
    const int l   = threadIdx.x & 63;
    const int sub = l >> 4;      // row-within-4-chunk
    const int m16 = l & 15;      // permuted col group: cols' 4*m16..+3
    for (int n = blockIdx.x * 4 + w; n < NN; n += gridDim.x * 4) {
        int ja = (n == 0) ? 0 : off[n - 1];
        int jb = off[n];
        int ka = off[NN + n - 1];   // n==0 -> off[NN-1] = start of k-region
        int kb = off[NN + n];
        float s0 = 0.f, s1 = 0.f, s2 = 0.f, s3 = 0.f;
        float t0 = 0.f, t1 = 0.f, t2 = 0.f, t3 = 0.f;
        for (int p = ja + sub; p < jb; p += 4) {
            f16x4 v = *(const f16x4*)(msg + (size_t)p * 64 + m16 * 4);
            s0 += (float)v[0]; s1 += (float)v[1];
            s2 += (float)v[2]; s3 += (float)v[3];
        }
        for (int p = ka + sub; p < kb; p += 4) {
            f16x4 v = *(const f16x4*)(msg + (size_t)p * 64 + m16 * 4);
            t0 += (float)v[0]; t1 += (float)v[1];
            t2 += (float)v[2]; t3 += (float)v[3];
        }
        s0 += __shfl_xor(s0, 16); s0 += __shfl_xor(s0, 32);
        s1 += __shfl_xor(s1, 16); s1 += __shfl_xor(s1, 32);
        s2 += __shfl_xor(s2, 16); s2 += __shfl_xor(s2, 32);
        s3 += __shfl_xor(s3, 16); s3 += __shfl_xor(s3, 32);
        t0 += __shfl_xor(t0, 16); t0 += __shfl_xor(t0, 32);
        t1 += __shfl_xor(t1, 16); t1 += __shfl_xor(t1, 32);
        t2 += __shfl_xor(t2, 16); t2 += __shfl_xor(t2, 32);
        t3 += __shfl_xor(t3, 16); t3 += __shfl_xor(t3, 32);
        if (sub == 0) {
            float rj = 1.0f / fmaxf((float)(jb - ja), 1.0f);
            float rk = 1.0f / fmaxf((float)(kb - ka), 1.0f);
            float* o = out + (size_t)n * 64;
            o[m16]      = s0 * rj + t0 * rk;   // col' 4m+nt <-> true col 16nt+m
            o[16 + m16] = s1 * rj + t1 * rk;
            o[32 + m16] = s2 * rj + t2 * rk;
            o[48 + m16] = s3 * rj + t3 * rk;
        }
    }
}

// ============================ launch ============================

extern "C" void kernel_launch(void* const* d_in, const int* in_sizes, int n_in,
                              void* d_out, int out_size, void* d_ws, size_t ws_size,
                              hipStream_t stream) {
    (void)in_sizes; (void)n_in; (void)out_size;

    const float* x     = (const float*)d_in[0];
    const float* pos   = (const float*)d_in[1];
    const int*   qidx  = (const int*)d_in[2];
    const float* qattr = (const float*)d_in[3];
    const float* gamma = (const float*)d_in[4];
    const float* beta  = (const float*)d_in[5];
    const float* w1    = (const float*)d_in[6];
    const float* b1    = (const float*)d_in[7];
    const float* w2    = (const float*)d_in[8];
    const float* b2    = (const float*)d_in[9];
    const float* w3    = (const float*)d_in[10];
    const float* b3    = (const float*)d_in[11];
    const float* w_out = (const float*)d_in[12];
    float* out = (float*)d_out;

    size_t o = 0;
    auto alloc = [&](size_t bytes) { size_t r = o; o = (o + bytes + 255) & ~(size_t)255; return r; };
    char* W = (char*)d_ws;
    f16*    msg    = (f16*)   (W + alloc((size_t)2 * ND * 64 * sizeof(f16)));
    int*    slot_j = (int*)   (W + alloc((size_t)ND * sizeof(int)));
    int*    slot_k = (int*)   (W + alloc((size_t)ND * sizeof(int)));
    int*    off    = (int*)   (W + alloc((size_t)NCNT * sizeof(int)));
    int*    bsum   = (int*)   (W + alloc((size_t)NBLK_SCAN * sizeof(int)));
    __bf16* w1h    = (__bf16*)(W + alloc((size_t)64 * K1P * sizeof(__bf16)));
    __bf16* w1l    = (__bf16*)(W + alloc((size_t)64 * K1P * sizeof(__bf16)));
    __bf16* w2h    = (__bf16*)(W + alloc((size_t)64 * 64 * sizeof(__bf16)));
    __bf16* w2l    = (__bf16*)(W + alloc((size_t)64 * 64 * sizeof(__bf16)));
    __bf16* w3h    = (__bf16*)(W + alloc((size_t)64 * 64 * sizeof(__bf16)));
    __bf16* w3l    = (__bf16*)(W + alloc((size_t)64 * 64 * sizeof(__bf16)));
    float*  gp     = (float*) (W + alloc((size_t)K1P * sizeof(float)));
    float*  bp     = (float*) (W + alloc((size_t)K1P * sizeof(float)));
    float*  b3f    = (float*) (W + alloc((size_t)64 * sizeof(float)));
    if (ws_size < o) return;

    // weight prep: w1 plain-k; w2 permuted-k; w3 folded with w_out, permuted-k
    prep_w<<<(64 * K1P + 255) / 256, 256, 0, stream>>>(w1, w1h, w1l, INDIM, K1P, 0);
    prep_w<<<(64 * 64 + 255) / 256, 256, 0, stream>>>(w2, w2h, w2l, 64, 64, 1);
    prep_w3<<<1, 256, 0, stream>>>(w3, b3, w_out, w3h, w3l, b3f);
    prep_gb<<<1, 256, 0, stream>>>(gamma, beta, gp, bp);

    // counting sort
    hipMemsetAsync(off, 0, (size_t)NCNT * sizeof(int), stream);
    count_kernel<<<(ND + 255) / 256, 256, 0, stream>>>(qidx, off);
    scan1<<<NBLK_SCAN, 256, 0, stream>>>(off, bsum);
    scan2<<<1, 128, 0, stream>>>(bsum);
    scan3<<<NBLK_SCAN, 256, 0, stream>>>(off, bsum);
    fill_kernel<<<(ND + 255) / 256, 256, 0, stream>>>(qidx, off, slot_j, slot_k);

    // edge MLP (MFMA, 32 edges/wave) -> sorted msg (w_out folded, permuted cols)
    edge_mlp_mfma<<<(ND + 127) / 128, 256, 0, stream>>>(x, pos, qidx, qattr, gp, bp,
                                                        w1h, w1l, b1, w2h, w2l, b2,
                                                        w3h, w3l, b3f, slot_j, slot_k, msg);
    // node aggregation (vectorized segmented mean)
    node_out<<<4096, 256, 0, stream>>>(msg, off, out);
}